// Round 1
// baseline (1746.380 us; speedup 1.0000x reference)
//
#include <hip/hip_runtime.h>
#include <math.h>

#define N_NODES 2048
#define BATCH   64
#define DIN     2
#define DOUT    64
#define CIN     66     // DIN + DOUT
#define CP      68     // padded channel count (16B alignment)
#define D_EMB   10
#define GOUT    128    // gate output channels (2*DOUT)
#define UOUT    64     // update output channels
#define NCOLS   (BATCH*CP)   // 4352, GEMM N dimension

// ---------------------------------------------------------------------------
// Kernel 1: S[n,m] = softmax_m(relu(E[n,:] . E[m,:]))
// One block per row n, 256 threads, 8 columns per thread.
__global__ __launch_bounds__(256) void supports_kernel(
    const float* __restrict__ E, float* __restrict__ S)
{
    const int n   = blockIdx.x;
    const int tid = threadIdx.x;

    float en[D_EMB];
#pragma unroll
    for (int d = 0; d < D_EMB; ++d) en[d] = E[n * D_EMB + d];

    float vals[8];
    float mx = -1e30f;
#pragma unroll
    for (int j = 0; j < 8; ++j) {
        const int m = tid + j * 256;
        float dot = 0.f;
#pragma unroll
        for (int d = 0; d < D_EMB; ++d) dot += en[d] * E[m * D_EMB + d];
        dot = fmaxf(dot, 0.f);
        vals[j] = dot;
        mx = fmaxf(mx, dot);
    }

    __shared__ float sred[4];
    // block max
    for (int off = 32; off > 0; off >>= 1) mx = fmaxf(mx, __shfl_xor(mx, off));
    if ((tid & 63) == 0) sred[tid >> 6] = mx;
    __syncthreads();
    mx = fmaxf(fmaxf(sred[0], sred[1]), fmaxf(sred[2], sred[3]));

    float sum = 0.f;
#pragma unroll
    for (int j = 0; j < 8; ++j) { vals[j] = __expf(vals[j] - mx); sum += vals[j]; }

    __syncthreads();   // protect sred reuse
    for (int off = 32; off > 0; off >>= 1) sum += __shfl_xor(sum, off);
    if ((tid & 63) == 0) sred[tid >> 6] = sum;
    __syncthreads();
    sum = sred[0] + sred[1] + sred[2] + sred[3];

    const float inv = 1.f / sum;
#pragma unroll
    for (int j = 0; j < 8; ++j) S[(size_t)n * N_NODES + tid + j * 256] = vals[j] * inv;
}

// ---------------------------------------------------------------------------
// Kernel 2: build X0[m][b][c] = concat(x, state) padded to CP channels.
__global__ __launch_bounds__(256) void concat_kernel(
    const float* __restrict__ x, const float* __restrict__ state,
    float* __restrict__ X0)
{
    const int idx = blockIdx.x * 256 + threadIdx.x;
    if (idx >= N_NODES * BATCH * CP) return;
    const int c  = idx % CP;
    const int mb = idx / CP;
    const int b  = mb % BATCH;
    const int m  = mb / BATCH;
    float v;
    if (c < DIN)      v = x[((size_t)b * N_NODES + m) * DIN + c];
    else if (c < CIN) v = state[((size_t)b * N_NODES + m) * DOUT + (c - DIN)];
    else              v = 0.f;
    X0[idx] = v;
}

// ---------------------------------------------------------------------------
// Kernel 3: fp32 SGEMM  C[M,NC] = A[M,K] * B[K,NC]
// 128x128 block tile, BK=8, 256 threads, 8x8 microtile.
__global__ __launch_bounds__(256) void sgemm_kernel(
    const float* __restrict__ A, const float* __restrict__ Bm,
    float* __restrict__ C, int M, int K, int NC)
{
    __shared__ float As[8][128];
    __shared__ float Bs[8][128];

    const int tid = threadIdx.x;
    const int bn  = blockIdx.x;   // N-block
    const int bm  = blockIdx.y;   // M-block
    const int tm  = tid & 15;
    const int tn  = tid >> 4;

    float acc[8][8];
#pragma unroll
    for (int i = 0; i < 8; ++i)
#pragma unroll
        for (int j = 0; j < 8; ++j) acc[i][j] = 0.f;

    const int arow = tid >> 1, acol = (tid & 1) * 4;   // A: 128 rows x 8 cols
    const int brow = tid >> 5, bcol = (tid & 31) * 4;  // B: 8 rows x 128 cols
    const float* Aptr = A + ((size_t)bm * 128 + arow) * K + acol;
    const float* Bptr = Bm + (size_t)brow * NC + bn * 128 + bcol;

    for (int k0 = 0; k0 < K; k0 += 8) {
        const float4 av = *(const float4*)(Aptr + k0);
        const float4 bv = *(const float4*)(Bptr + (size_t)k0 * NC);
        __syncthreads();
        As[acol + 0][arow] = av.x;
        As[acol + 1][arow] = av.y;
        As[acol + 2][arow] = av.z;
        As[acol + 3][arow] = av.w;
        *(float4*)&Bs[brow][bcol] = bv;
        __syncthreads();
#pragma unroll
        for (int kk = 0; kk < 8; ++kk) {
            float a[8], b[8];
            *(float4*)(a)     = *(const float4*)&As[kk][tm * 4];
            *(float4*)(a + 4) = *(const float4*)&As[kk][64 + tm * 4];
            *(float4*)(b)     = *(const float4*)&Bs[kk][tn * 4];
            *(float4*)(b + 4) = *(const float4*)&Bs[kk][64 + tn * 4];
#pragma unroll
            for (int i = 0; i < 8; ++i)
#pragma unroll
                for (int j = 0; j < 8; ++j) acc[i][j] += a[i] * b[j];
        }
    }

#pragma unroll
    for (int ih = 0; ih < 2; ++ih)
#pragma unroll
        for (int i = 0; i < 4; ++i) {
            const int r = bm * 128 + ih * 64 + tm * 4 + i;
            float* Crow = C + (size_t)r * NC + bn * 128;
            *(float4*)&Crow[tn * 4] = make_float4(
                acc[ih * 4 + i][0], acc[ih * 4 + i][1],
                acc[ih * 4 + i][2], acc[ih * 4 + i][3]);
            *(float4*)&Crow[64 + tn * 4] = make_float4(
                acc[ih * 4 + i][4], acc[ih * 4 + i][5],
                acc[ih * 4 + i][6], acc[ih * 4 + i][7]);
        }
}

// ---------------------------------------------------------------------------
// Kernel 4: gate transform. One block per node n.
// pre[b,o] = bias[o] + sum_i X0[n,b,i]*W0[i,o] + AG[n,b,i]*W1[i,o]
// z = sigmoid(pre[:,:64]) -> candidate (in-place into X0); r = sigmoid(pre[:,64:]) -> Rbuf
__global__ __launch_bounds__(256) void gate_transform_kernel(
    const float* __restrict__ E, const float* __restrict__ wp,
    const float* __restrict__ bp, const float* __restrict__ X0,
    const float* __restrict__ AG, const float* __restrict__ x,
    const float* __restrict__ state,
    float* __restrict__ X1, float* __restrict__ Rbuf)
{
    const int n   = blockIdx.x;
    const int tid = threadIdx.x;

    __shared__ float W[CIN][GOUT][2];     // [i][o][k]
    __shared__ float bias[GOUT];
    __shared__ float crow[2][CIN][2];     // [bl][i][k] k=0:X0 k=1:AG

    float en[D_EMB];
#pragma unroll
    for (int d = 0; d < D_EMB; ++d) en[d] = E[n * D_EMB + d];

    // weights: wp[d][k][i][o], 2*66*128 = 16896 = 66*256
    for (int idx = tid; idx < 2 * CIN * GOUT; idx += 256) {
        const int k = idx / (CIN * GOUT);
        const int rem = idx % (CIN * GOUT);
        const int i = rem / GOUT;
        const int o = rem % GOUT;
        float s = 0.f;
#pragma unroll
        for (int d = 0; d < D_EMB; ++d)
            s += en[d] * wp[(((size_t)d * 2 + k) * CIN + i) * GOUT + o];
        W[i][o][k] = s;
    }
    if (tid < GOUT) {
        float s = 0.f;
#pragma unroll
        for (int d = 0; d < D_EMB; ++d) s += en[d] * bp[d * GOUT + tid];
        bias[tid] = s;
    }
    __syncthreads();

    const int bl = tid >> 7;       // 0..1
    const int o  = tid & 127;      // 0..127

    for (int bb = 0; bb < BATCH; bb += 2) {
        for (int idx = tid; idx < 2 * CIN * 2; idx += 256) {
            const int l   = idx / (CIN * 2);
            const int rem = idx % (CIN * 2);
            const int i   = rem >> 1;
            const int k   = rem & 1;
            const size_t base = ((size_t)n * BATCH + bb + l) * CP + i;
            crow[l][i][k] = k ? AG[base] : X0[base];
        }
        __syncthreads();

        const int b = bb + bl;
        float pre = bias[o];
#pragma unroll
        for (int i = 0; i < CIN; ++i)
            pre += crow[bl][i][0] * W[i][o][0] + crow[bl][i][1] * W[i][o][1];

        const float sg = 1.f / (1.f + __expf(-pre));
        if (o < DOUT) {
            const float zs = sg * state[((size_t)b * N_NODES + n) * DOUT + o];
            X1[((size_t)n * BATCH + b) * CP + DIN + o] = zs;
        } else {
            Rbuf[((size_t)n * BATCH + b) * DOUT + (o - DOUT)] = sg;
        }
        if (o < DIN)
            X1[((size_t)n * BATCH + b) * CP + o] = x[((size_t)b * N_NODES + n) * DIN + o];
        if (o >= DOUT && o < DOUT + 2)
            X1[((size_t)n * BATCH + b) * CP + CIN + (o - DOUT)] = 0.f;
        __syncthreads();
    }
}

// ---------------------------------------------------------------------------
// Kernel 5: update transform + GRU output. One block per node.
// hc = tanh(bias + X1*W0 + AG*W1); h = r*state + (1-r)*hc
__global__ __launch_bounds__(256) void update_final_kernel(
    const float* __restrict__ E, const float* __restrict__ wp,
    const float* __restrict__ bp, const float* __restrict__ X1,
    const float* __restrict__ AG, const float* __restrict__ state,
    const float* __restrict__ Rbuf, float* __restrict__ out)
{
    const int n   = blockIdx.x;
    const int tid = threadIdx.x;

    __shared__ float W[CIN][UOUT][2];
    __shared__ float bias[UOUT];
    __shared__ float crow[4][CIN][2];

    float en[D_EMB];
#pragma unroll
    for (int d = 0; d < D_EMB; ++d) en[d] = E[n * D_EMB + d];

    for (int idx = tid; idx < 2 * CIN * UOUT; idx += 256) {
        const int k = idx / (CIN * UOUT);
        const int rem = idx % (CIN * UOUT);
        const int i = rem / UOUT;
        const int o = rem % UOUT;
        float s = 0.f;
#pragma unroll
        for (int d = 0; d < D_EMB; ++d)
            s += en[d] * wp[(((size_t)d * 2 + k) * CIN + i) * UOUT + o];
        W[i][o][k] = s;
    }
    if (tid < UOUT) {
        float s = 0.f;
#pragma unroll
        for (int d = 0; d < D_EMB; ++d) s += en[d] * bp[d * UOUT + tid];
        bias[tid] = s;
    }
    __syncthreads();

    const int bl = tid >> 6;      // 0..3
    const int o  = tid & 63;

    for (int bb = 0; bb < BATCH; bb += 4) {
        for (int idx = tid; idx < 4 * CIN * 2; idx += 256) {
            const int l   = idx / (CIN * 2);
            const int rem = idx % (CIN * 2);
            const int i   = rem >> 1;
            const int k   = rem & 1;
            const size_t base = ((size_t)n * BATCH + bb + l) * CP + i;
            crow[l][i][k] = k ? AG[base] : X1[base];
        }
        __syncthreads();

        const int b = bb + bl;
        float pre = bias[o];
#pragma unroll
        for (int i = 0; i < CIN; ++i)
            pre += crow[bl][i][0] * W[i][o][0] + crow[bl][i][1] * W[i][o][1];

        const float hc = tanhf(pre);
        const float rr = Rbuf[((size_t)n * BATCH + b) * DOUT + o];
        const float st = state[((size_t)b * N_NODES + n) * DOUT + o];
        out[((size_t)b * N_NODES + n) * DOUT + o] = rr * st + (1.f - rr) * hc;
        __syncthreads();
    }
}

// ---------------------------------------------------------------------------
extern "C" void kernel_launch(void* const* d_in, const int* in_sizes, int n_in,
                              void* d_out, int out_size, void* d_ws, size_t ws_size,
                              hipStream_t stream)
{
    const float* x  = (const float*)d_in[0];
    const float* st = (const float*)d_in[1];
    const float* E  = (const float*)d_in[2];
    const float* gw = (const float*)d_in[3];
    const float* gb = (const float*)d_in[4];
    const float* uw = (const float*)d_in[5];
    const float* ub = (const float*)d_in[6];
    float* out = (float*)d_out;

    float* ws = (float*)d_ws;
    float* S  = ws;                                      // N*N
    float* X0 = S  + (size_t)N_NODES * N_NODES;          // N*B*CP
    float* AG = X0 + (size_t)N_NODES * BATCH * CP;       // N*B*CP
    float* Rb = AG + (size_t)N_NODES * BATCH * CP;       // N*B*DOUT

    supports_kernel<<<N_NODES, 256, 0, stream>>>(E, S);
    concat_kernel<<<(N_NODES * BATCH * CP + 255) / 256, 256, 0, stream>>>(x, st, X0);
    sgemm_kernel<<<dim3(NCOLS / 128, N_NODES / 128), 256, 0, stream>>>(
        S, X0, AG, N_NODES, N_NODES, NCOLS);
    gate_transform_kernel<<<N_NODES, 256, 0, stream>>>(
        E, gw, gb, X0, AG, x, st, X0 /*in-place candidate*/, Rb);
    sgemm_kernel<<<dim3(NCOLS / 128, N_NODES / 128), 256, 0, stream>>>(
        S, X0, AG, N_NODES, N_NODES, NCOLS);
    update_final_kernel<<<N_NODES, 256, 0, stream>>>(
        E, uw, ub, X0, AG, st, Rb, out);
}

// Round 3
// 970.349 us; speedup vs baseline: 1.7997x; 1.7997x over previous
//
#include <hip/hip_runtime.h>
#include <math.h>

#define N_NODES 2048
#define BATCH   64
#define DIN     2
#define DOUT    64
#define CIN     66     // DIN + DOUT
#define CP      68     // padded channel count
#define D_EMB   10
#define GOUT    128    // gate output channels (2*DOUT)
#define UOUT    64     // update output channels
#define NCOLS   (BATCH*CP)   // 4352, GEMM N dimension
#define MK      2048         // GEMM K per pass

typedef __attribute__((ext_vector_type(8))) short bf16x8;
typedef __attribute__((ext_vector_type(8))) unsigned short u16x8;
typedef __attribute__((ext_vector_type(4))) float f32x4;

__device__ __forceinline__ unsigned short f2bf_rn(float f) {
    unsigned u = __builtin_bit_cast(unsigned, f);
    unsigned r = u + 0x7FFFu + ((u >> 16) & 1u);   // RNE
    return (unsigned short)(r >> 16);
}
__device__ __forceinline__ float bf2f(unsigned short h) {
    unsigned u = ((unsigned)h) << 16;
    return __builtin_bit_cast(float, u);
}

__device__ __forceinline__ void gload_lds16(const void* g, void* l) {
    __builtin_amdgcn_global_load_lds(
        (const __attribute__((address_space(1))) unsigned int*)g,
        (__attribute__((address_space(3))) unsigned int*)l, 16, 0, 0);
}

// ---------------------------------------------------------------------------
// Kernel 1: S[n,m] = softmax_m(relu(E[n,:].E[m,:])) emitted as bf16 hi+lo.
__global__ __launch_bounds__(256) void supports_kernel(
    const float* __restrict__ E,
    unsigned short* __restrict__ S_hi, unsigned short* __restrict__ S_lo)
{
    const int n   = blockIdx.x;
    const int tid = threadIdx.x;

    float en[D_EMB];
#pragma unroll
    for (int d = 0; d < D_EMB; ++d) en[d] = E[n * D_EMB + d];

    float vals[8];
    float mx = -1e30f;
#pragma unroll
    for (int j = 0; j < 8; ++j) {
        const int m = tid + j * 256;
        float dot = 0.f;
#pragma unroll
        for (int d = 0; d < D_EMB; ++d) dot += en[d] * E[m * D_EMB + d];
        dot = fmaxf(dot, 0.f);
        vals[j] = dot;
        mx = fmaxf(mx, dot);
    }

    __shared__ float sred[4];
    for (int off = 32; off > 0; off >>= 1) mx = fmaxf(mx, __shfl_xor(mx, off));
    if ((tid & 63) == 0) sred[tid >> 6] = mx;
    __syncthreads();
    mx = fmaxf(fmaxf(sred[0], sred[1]), fmaxf(sred[2], sred[3]));

    float sum = 0.f;
#pragma unroll
    for (int j = 0; j < 8; ++j) { vals[j] = __expf(vals[j] - mx); sum += vals[j]; }

    __syncthreads();
    for (int off = 32; off > 0; off >>= 1) sum += __shfl_xor(sum, off);
    if ((tid & 63) == 0) sred[tid >> 6] = sum;
    __syncthreads();
    sum = sred[0] + sred[1] + sred[2] + sred[3];

    const float inv = 1.f / sum;
#pragma unroll
    for (int j = 0; j < 8; ++j) {
        const float v = vals[j] * inv;
        const unsigned short h = f2bf_rn(v);
        const size_t idx = (size_t)n * N_NODES + tid + j * 256;
        S_hi[idx] = h;
        S_lo[idx] = f2bf_rn(v - bf2f(h));
    }
}

// ---------------------------------------------------------------------------
// Kernel 2: build XT[j][m] (bf16), j = b*CP + c, c = concat(x, state|zs) padded.
// Tiled transpose: block = (64 m) x (all c) for one b.
// zs (when use_zs) is bf16 [m][b][DOUT]; state is f32 [b][m][DOUT].
__global__ __launch_bounds__(256) void build_xt_kernel(
    const float* __restrict__ x, const float* __restrict__ state,
    const unsigned short* __restrict__ zs, const int use_zs,
    unsigned short* __restrict__ XT)
{
    const int b   = blockIdx.y;
    const int m0  = blockIdx.x * 64;
    const int tid = threadIdx.x;
    __shared__ float T[64][69];   // +1 pad: stride 69 -> conflict-free column reads

    {
        const int r = tid >> 2;
        const int q = (tid & 3) * 16;
        if (use_zs) {
            const u16x8 v0 = *(const u16x8*)&zs[((size_t)(m0 + r) * BATCH + b) * DOUT + q];
            const u16x8 v1 = *(const u16x8*)&zs[((size_t)(m0 + r) * BATCH + b) * DOUT + q + 8];
#pragma unroll
            for (int u = 0; u < 8; ++u) {
                T[r][DIN + q + u]     = bf2f(v0[u]);
                T[r][DIN + q + 8 + u] = bf2f(v1[u]);
            }
        } else {
#pragma unroll
            for (int u = 0; u < 4; ++u) {
                const float4 v = *(const float4*)&state[((size_t)b * N_NODES + m0 + r) * DOUT + q + u * 4];
                T[r][DIN + q + u * 4 + 0] = v.x;
                T[r][DIN + q + u * 4 + 1] = v.y;
                T[r][DIN + q + u * 4 + 2] = v.z;
                T[r][DIN + q + u * 4 + 3] = v.w;
            }
        }
    }
    if (tid < 128) {
        const int r = tid >> 1, c = tid & 1;
        T[r][c] = x[((size_t)b * N_NODES + m0 + r) * DIN + c];
        T[r][CIN + c] = 0.f;   // pad channels 66,67
    }
    __syncthreads();

    for (int idx = tid; idx < CP * 64; idx += 256) {
        const int c  = idx >> 6;
        const int mm = idx & 63;
        XT[((size_t)(b * CP + c)) * N_NODES + m0 + mm] = f2bf_rn(T[mm][c]);
    }
}

// ---------------------------------------------------------------------------
// Kernel 3: bf16 MFMA GEMM  C[M,NC] = (Ahi+Alo)[M,K] * B[K,NC]
// A row-major [M][K] bf16 (hi+lo 2-pass); B given transposed XT[NC][K] bf16.
// 128x128 tile, BK=32, 4 waves, 4x4 16x16x32 frags/wave, fragment-order LDS
// staged with global_load_lds(16B) using pre-swizzled global addresses.
__global__ __launch_bounds__(256) void gemm_mfma_kernel(
    const unsigned short* __restrict__ Ahi, const unsigned short* __restrict__ Alo,
    const unsigned short* __restrict__ BT, float* __restrict__ C)
{
    __shared__ __align__(16) unsigned short As[4096];  // 8 KB, fragment order
    __shared__ __align__(16) unsigned short Bs[4096];

    const int tid  = threadIdx.x;
    const int lane = tid & 63;
    const int w    = tid >> 6;
    const int wr   = w >> 1, wc = w & 1;
    const int bn   = blockIdx.x;   // NC/128 = 34
    const int bm   = blockIdx.y;   // M/128 = 16

    f32x4 acc[4][4];
#pragma unroll
    for (int i = 0; i < 4; ++i)
#pragma unroll
        for (int j = 0; j < 4; ++j) acc[i][j] = (f32x4){0.f, 0.f, 0.f, 0.f};

    // staging decomposition: LDS entry e (16B) holds row (e>>6)*16+(e&15),
    // k-slice ((e>>4)&3)*8 of the tile. Thread t stages entries t and t+256.
    const int srow = ((tid >> 6) << 4) + (tid & 15);
    const int scol = ((tid >> 4) & 3) * 8;
    const unsigned a_off0 = (unsigned)(bm * 128 + srow) * MK + scol;
    const unsigned a_off1 = a_off0 + 64u * MK;
    const unsigned b_off0 = (unsigned)(bn * 128 + srow) * MK + scol;
    const unsigned b_off1 = b_off0 + 64u * MK;

    unsigned short* asl0 = As + tid * 8;
    unsigned short* asl1 = As + 2048 + tid * 8;
    unsigned short* bsl0 = Bs + tid * 8;
    unsigned short* bsl1 = Bs + 2048 + tid * 8;

#pragma unroll 1
    for (int pass = 0; pass < 2; ++pass) {
        const unsigned short* Ap = (pass == 0) ? Ahi : Alo;
#pragma unroll 1
        for (int k0 = 0; k0 < MK; k0 += 32) {
            gload_lds16(Ap + a_off0 + k0, asl0);
            gload_lds16(Ap + a_off1 + k0, asl1);
            gload_lds16(BT + b_off0 + k0, bsl0);
            gload_lds16(BT + b_off1 + k0, bsl1);
            __syncthreads();   // drains vmcnt(0): tiles visible

            bf16x8 af[4], bf[4];
#pragma unroll
            for (int i = 0; i < 4; ++i)
                af[i] = *(const bf16x8*)(As + ((wr * 4 + i) * 64 + lane) * 8);
#pragma unroll
            for (int j = 0; j < 4; ++j)
                bf[j] = *(const bf16x8*)(Bs + ((wc * 4 + j) * 64 + lane) * 8);
#pragma unroll
            for (int i = 0; i < 4; ++i)
#pragma unroll
                for (int j = 0; j < 4; ++j)
                    acc[i][j] = __builtin_amdgcn_mfma_f32_16x16x32_bf16(
                        af[i], bf[j], acc[i][j], 0, 0, 0);
            __syncthreads();   // protect LDS before next-tile overwrite
        }
    }

    const int crow0 = bm * 128 + wr * 64;
    const int ccol0 = bn * 128 + wc * 64;
#pragma unroll
    for (int i = 0; i < 4; ++i)
#pragma unroll
        for (int j = 0; j < 4; ++j)
#pragma unroll
            for (int r = 0; r < 4; ++r) {
                const int row = crow0 + i * 16 + (lane >> 4) * 4 + r;
                const int col = ccol0 + j * 16 + (lane & 15);
                C[(size_t)row * NCOLS + col] = acc[i][j][r];
            }
}

// ---------------------------------------------------------------------------
// Kernel 4: gate transform. One block per node n.
// pre[b,o] = bias[o] + sum_i cat(x,state)[b,i]*W0[i,o] + AG[b,i]*W1[i,o]
// z=sigmoid(pre[:,:64]) -> ZS = bf16(z*state) ; r=sigmoid(pre[:,64:]) -> Rbuf
__global__ __launch_bounds__(256) void gate_transform_kernel(
    const float* __restrict__ E, const float* __restrict__ wp,
    const float* __restrict__ bp, const float* __restrict__ x,
    const float* __restrict__ state, const float* __restrict__ AG,
    unsigned short* __restrict__ ZS, float* __restrict__ Rbuf)
{
    const int n   = blockIdx.x;
    const int tid = threadIdx.x;

    __shared__ float W[CIN][GOUT][2];     // [i][o][k]
    __shared__ float bias[GOUT];
    __shared__ float crow[2][CIN][2];     // [bl][i][k] k=0:concat k=1:AG

    float en[D_EMB];
#pragma unroll
    for (int d = 0; d < D_EMB; ++d) en[d] = E[n * D_EMB + d];

    for (int idx = tid; idx < 2 * CIN * GOUT; idx += 256) {
        const int k = idx / (CIN * GOUT);
        const int rem = idx % (CIN * GOUT);
        const int i = rem / GOUT;
        const int o = rem % GOUT;
        float s = 0.f;
#pragma unroll
        for (int d = 0; d < D_EMB; ++d)
            s += en[d] * wp[(((size_t)d * 2 + k) * CIN + i) * GOUT + o];
        W[i][o][k] = s;
    }
    if (tid < GOUT) {
        float s = 0.f;
#pragma unroll
        for (int d = 0; d < D_EMB; ++d) s += en[d] * bp[d * GOUT + tid];
        bias[tid] = s;
    }
    __syncthreads();

    const int bl = tid >> 7;       // 0..1
    const int o  = tid & 127;      // 0..127

    for (int bb = 0; bb < BATCH; bb += 2) {
        for (int idx = tid; idx < 2 * CIN * 2; idx += 256) {
            const int l   = idx / (CIN * 2);
            const int rem = idx % (CIN * 2);
            const int i   = rem >> 1;
            const int k   = rem & 1;
            const int b   = bb + l;
            float v;
            if (k)            v = AG[(size_t)n * NCOLS + b * CP + i];
            else if (i < DIN) v = x[((size_t)b * N_NODES + n) * DIN + i];
            else              v = state[((size_t)b * N_NODES + n) * DOUT + (i - DIN)];
            crow[l][i][k] = v;
        }
        __syncthreads();

        const int b = bb + bl;
        float pre = bias[o];
#pragma unroll
        for (int i = 0; i < CIN; ++i)
            pre += crow[bl][i][0] * W[i][o][0] + crow[bl][i][1] * W[i][o][1];

        const float sg = 1.f / (1.f + __expf(-pre));
        if (o < DOUT) {
            ZS[((size_t)n * BATCH + b) * DOUT + o] =
                f2bf_rn(sg * state[((size_t)b * N_NODES + n) * DOUT + o]);
        } else {
            Rbuf[((size_t)n * BATCH + b) * DOUT + (o - DOUT)] = sg;
        }
        __syncthreads();
    }
}

// ---------------------------------------------------------------------------
// Kernel 5: update transform + GRU output. One block per node.
__global__ __launch_bounds__(256) void update_final_kernel(
    const float* __restrict__ E, const float* __restrict__ wp,
    const float* __restrict__ bp, const float* __restrict__ x,
    const unsigned short* __restrict__ ZS, const float* __restrict__ AG,
    const float* __restrict__ state, const float* __restrict__ Rbuf,
    float* __restrict__ out)
{
    const int n   = blockIdx.x;
    const int tid = threadIdx.x;

    __shared__ float W[CIN][UOUT][2];
    __shared__ float bias[UOUT];
    __shared__ float crow[4][CIN][2];

    float en[D_EMB];
#pragma unroll
    for (int d = 0; d < D_EMB; ++d) en[d] = E[n * D_EMB + d];

    for (int idx = tid; idx < 2 * CIN * UOUT; idx += 256) {
        const int k = idx / (CIN * UOUT);
        const int rem = idx % (CIN * UOUT);
        const int i = rem / UOUT;
        const int o = rem % UOUT;
        float s = 0.f;
#pragma unroll
        for (int d = 0; d < D_EMB; ++d)
            s += en[d] * wp[(((size_t)d * 2 + k) * CIN + i) * UOUT + o];
        W[i][o][k] = s;
    }
    if (tid < UOUT) {
        float s = 0.f;
#pragma unroll
        for (int d = 0; d < D_EMB; ++d) s += en[d] * bp[d * UOUT + tid];
        bias[tid] = s;
    }
    __syncthreads();

    const int bl = tid >> 6;      // 0..3
    const int o  = tid & 63;

    for (int bb = 0; bb < BATCH; bb += 4) {
        for (int idx = tid; idx < 4 * CIN * 2; idx += 256) {
            const int l   = idx / (CIN * 2);
            const int rem = idx % (CIN * 2);
            const int i   = rem >> 1;
            const int k   = rem & 1;
            const int b   = bb + l;
            float v;
            if (k)            v = AG[(size_t)n * NCOLS + b * CP + i];
            else if (i < DIN) v = x[((size_t)b * N_NODES + n) * DIN + i];
            else              v = bf2f(ZS[((size_t)n * BATCH + b) * DOUT + (i - DIN)]);
            crow[l][i][k] = v;
        }
        __syncthreads();

        const int b = bb + bl;
        float pre = bias[o];
#pragma unroll
        for (int i = 0; i < CIN; ++i)
            pre += crow[bl][i][0] * W[i][o][0] + crow[bl][i][1] * W[i][o][1];

        const float hc = tanhf(pre);
        const float rr = Rbuf[((size_t)n * BATCH + b) * DOUT + o];
        const float st = state[((size_t)b * N_NODES + n) * DOUT + o];
        out[((size_t)b * N_NODES + n) * DOUT + o] = rr * st + (1.f - rr) * hc;
        __syncthreads();
    }
}

// ---------------------------------------------------------------------------
extern "C" void kernel_launch(void* const* d_in, const int* in_sizes, int n_in,
                              void* d_out, int out_size, void* d_ws, size_t ws_size,
                              hipStream_t stream)
{
    const float* x  = (const float*)d_in[0];
    const float* st = (const float*)d_in[1];
    const float* E  = (const float*)d_in[2];
    const float* gw = (const float*)d_in[3];
    const float* gb = (const float*)d_in[4];
    const float* uw = (const float*)d_in[5];
    const float* ub = (const float*)d_in[6];
    float* out = (float*)d_out;

    // workspace layout (~120.6 MB, under the 121.8 MB round-1 high-water mark)
    unsigned short* S_hi = (unsigned short*)d_ws;                  // 2048*2048 bf16
    unsigned short* S_lo = S_hi + (size_t)N_NODES * N_NODES;       // 2048*2048 bf16
    unsigned short* XT   = S_lo + (size_t)N_NODES * N_NODES;       // 4352*2048 bf16
    float* AG = (float*)(XT + (size_t)NCOLS * N_NODES);            // 2048*4352 f32
    unsigned short* ZS = (unsigned short*)(AG + (size_t)N_NODES * NCOLS); // 2048*64*64 bf16
    float* Rb = (float*)(ZS + (size_t)N_NODES * BATCH * DOUT);     // 2048*64*64 f32

    supports_kernel<<<N_NODES, 256, 0, stream>>>(E, S_hi, S_lo);
    build_xt_kernel<<<dim3(N_NODES / 64, BATCH), 256, 0, stream>>>(x, st, ZS, 0, XT);
    gemm_mfma_kernel<<<dim3(NCOLS / 128, N_NODES / 128), 256, 0, stream>>>(
        S_hi, S_lo, XT, AG);
    gate_transform_kernel<<<N_NODES, 256, 0, stream>>>(E, gw, gb, x, st, AG, ZS, Rb);
    build_xt_kernel<<<dim3(N_NODES / 64, BATCH), 256, 0, stream>>>(x, st, ZS, 1, XT);
    gemm_mfma_kernel<<<dim3(NCOLS / 128, N_NODES / 128), 256, 0, stream>>>(
        S_hi, S_lo, XT, AG);
    update_final_kernel<<<N_NODES, 256, 0, stream>>>(E, uw, ub, x, ZS, AG, st, Rb, out);
}

// Round 4
// 572.183 us; speedup vs baseline: 3.0521x; 1.6959x over previous
//
#include <hip/hip_runtime.h>
#include <math.h>

#define N_NODES 2048
#define BATCH   64
#define DIN     2
#define DOUT    64
#define CIN     66     // DIN + DOUT
#define CP      68     // padded channel count
#define D_EMB   10
#define GOUT    128    // gate output channels (2*DOUT)
#define NCOLS   (BATCH*CP)   // 4352, GEMM N dimension
#define MK      2048         // GEMM K
#define KTOT    132          // 2*CIN: flattened (k, i) contraction axis
#define LP      68           // LDS row pitch for W/IN tiles (16B-aligned, bank-spread)

typedef __attribute__((ext_vector_type(8))) short bf16x8;
typedef __attribute__((ext_vector_type(8))) unsigned short u16x8;
typedef __attribute__((ext_vector_type(4))) float f32x4;

__device__ __forceinline__ unsigned short f2bf_rn(float f) {
    unsigned u = __builtin_bit_cast(unsigned, f);
    unsigned r = u + 0x7FFFu + ((u >> 16) & 1u);   // RNE
    return (unsigned short)(r >> 16);
}
__device__ __forceinline__ float bf2f(unsigned short h) {
    unsigned u = ((unsigned)h) << 16;
    return __builtin_bit_cast(float, u);
}

__device__ __forceinline__ void gload_lds16(const void* g, void* l) {
    __builtin_amdgcn_global_load_lds(
        (const __attribute__((address_space(1))) unsigned int*)g,
        (__attribute__((address_space(3))) unsigned int*)l, 16, 0, 0);
}

// ---------------------------------------------------------------------------
// Kernel 1: S[n,m] = softmax_m(relu(E[n,:].E[m,:])) emitted as bf16.
__global__ __launch_bounds__(256) void supports_kernel(
    const float* __restrict__ E, unsigned short* __restrict__ S_hi)
{
    const int n   = blockIdx.x;
    const int tid = threadIdx.x;

    float en[D_EMB];
#pragma unroll
    for (int d = 0; d < D_EMB; ++d) en[d] = E[n * D_EMB + d];

    float vals[8];
    float mx = -1e30f;
#pragma unroll
    for (int j = 0; j < 8; ++j) {
        const int m = tid + j * 256;
        float dot = 0.f;
#pragma unroll
        for (int d = 0; d < D_EMB; ++d) dot += en[d] * E[m * D_EMB + d];
        dot = fmaxf(dot, 0.f);
        vals[j] = dot;
        mx = fmaxf(mx, dot);
    }

    __shared__ float sred[4];
    for (int off = 32; off > 0; off >>= 1) mx = fmaxf(mx, __shfl_xor(mx, off));
    if ((tid & 63) == 0) sred[tid >> 6] = mx;
    __syncthreads();
    mx = fmaxf(fmaxf(sred[0], sred[1]), fmaxf(sred[2], sred[3]));

    float sum = 0.f;
#pragma unroll
    for (int j = 0; j < 8; ++j) { vals[j] = __expf(vals[j] - mx); sum += vals[j]; }

    __syncthreads();
    for (int off = 32; off > 0; off >>= 1) sum += __shfl_xor(sum, off);
    if ((tid & 63) == 0) sred[tid >> 6] = sum;
    __syncthreads();
    sum = sred[0] + sred[1] + sred[2] + sred[3];

    const float inv = 1.f / sum;
#pragma unroll
    for (int j = 0; j < 8; ++j)
        S_hi[(size_t)n * N_NODES + tid + j * 256] = f2bf_rn(vals[j] * inv);
}

// ---------------------------------------------------------------------------
// Kernel 2: build XT[j][m] (bf16), j = b*CP + c, c = concat(x, state|zs) padded.
__global__ __launch_bounds__(256) void build_xt_kernel(
    const float* __restrict__ x, const float* __restrict__ state,
    const unsigned short* __restrict__ zs, const int use_zs,
    unsigned short* __restrict__ XT)
{
    const int b   = blockIdx.y;
    const int m0  = blockIdx.x * 64;
    const int tid = threadIdx.x;
    __shared__ float T[64][69];   // +1 pad: conflict-free column reads

    {
        const int r = tid >> 2;
        const int q = (tid & 3) * 16;
        if (use_zs) {
            const u16x8 v0 = *(const u16x8*)&zs[((size_t)(m0 + r) * BATCH + b) * DOUT + q];
            const u16x8 v1 = *(const u16x8*)&zs[((size_t)(m0 + r) * BATCH + b) * DOUT + q + 8];
#pragma unroll
            for (int u = 0; u < 8; ++u) {
                T[r][DIN + q + u]     = bf2f(v0[u]);
                T[r][DIN + q + 8 + u] = bf2f(v1[u]);
            }
        } else {
#pragma unroll
            for (int u = 0; u < 4; ++u) {
                const float4 v = *(const float4*)&state[((size_t)b * N_NODES + m0 + r) * DOUT + q + u * 4];
                T[r][DIN + q + u * 4 + 0] = v.x;
                T[r][DIN + q + u * 4 + 1] = v.y;
                T[r][DIN + q + u * 4 + 2] = v.z;
                T[r][DIN + q + u * 4 + 3] = v.w;
            }
        }
    }
    if (tid < 128) {
        const int r = tid >> 1, c = tid & 1;
        T[r][c] = x[((size_t)b * N_NODES + m0 + r) * DIN + c];
        T[r][CIN + c] = 0.f;   // pad channels 66,67
    }
    __syncthreads();

    for (int idx = tid; idx < CP * 64; idx += 256) {
        const int c  = idx >> 6;
        const int mm = idx & 63;
        XT[((size_t)(b * CP + c)) * N_NODES + m0 + mm] = f2bf_rn(T[mm][c]);
    }
}

// ---------------------------------------------------------------------------
// Kernel 3: bf16 MFMA GEMM  C[M,NC] = A[M,K] * B[K,NC]  (single pass)
__global__ __launch_bounds__(256) void gemm_mfma_kernel(
    const unsigned short* __restrict__ A,
    const unsigned short* __restrict__ BT, float* __restrict__ C)
{
    __shared__ __align__(16) unsigned short As[4096];  // 8 KB, fragment order
    __shared__ __align__(16) unsigned short Bs[4096];

    const int tid  = threadIdx.x;
    const int lane = tid & 63;
    const int w    = tid >> 6;
    const int wr   = w >> 1, wc = w & 1;
    const int bn   = blockIdx.x;   // NC/128 = 34
    const int bm   = blockIdx.y;   // M/128 = 16

    f32x4 acc[4][4];
#pragma unroll
    for (int i = 0; i < 4; ++i)
#pragma unroll
        for (int j = 0; j < 4; ++j) acc[i][j] = (f32x4){0.f, 0.f, 0.f, 0.f};

    const int srow = ((tid >> 6) << 4) + (tid & 15);
    const int scol = ((tid >> 4) & 3) * 8;
    const unsigned a_off0 = (unsigned)(bm * 128 + srow) * MK + scol;
    const unsigned a_off1 = a_off0 + 64u * MK;
    const unsigned b_off0 = (unsigned)(bn * 128 + srow) * MK + scol;
    const unsigned b_off1 = b_off0 + 64u * MK;

    unsigned short* asl0 = As + tid * 8;
    unsigned short* asl1 = As + 2048 + tid * 8;
    unsigned short* bsl0 = Bs + tid * 8;
    unsigned short* bsl1 = Bs + 2048 + tid * 8;

#pragma unroll 1
    for (int k0 = 0; k0 < MK; k0 += 32) {
        gload_lds16(A  + a_off0 + k0, asl0);
        gload_lds16(A  + a_off1 + k0, asl1);
        gload_lds16(BT + b_off0 + k0, bsl0);
        gload_lds16(BT + b_off1 + k0, bsl1);
        __syncthreads();   // drains vmcnt(0): tiles visible

        bf16x8 af[4], bf[4];
#pragma unroll
        for (int i = 0; i < 4; ++i)
            af[i] = *(const bf16x8*)(As + ((wr * 4 + i) * 64 + lane) * 8);
#pragma unroll
        for (int j = 0; j < 4; ++j)
            bf[j] = *(const bf16x8*)(Bs + ((wc * 4 + j) * 64 + lane) * 8);
#pragma unroll
        for (int i = 0; i < 4; ++i)
#pragma unroll
            for (int j = 0; j < 4; ++j)
                acc[i][j] = __builtin_amdgcn_mfma_f32_16x16x32_bf16(
                    af[i], bf[j], acc[i][j], 0, 0, 0);
        __syncthreads();
    }

    const int crow0 = bm * 128 + wr * 64;
    const int ccol0 = bn * 128 + wc * 64;
#pragma unroll
    for (int i = 0; i < 4; ++i)
#pragma unroll
        for (int j = 0; j < 4; ++j)
#pragma unroll
            for (int r = 0; r < 4; ++r) {
                const int row = crow0 + i * 16 + (lane >> 4) * 4 + r;
                const int col = ccol0 + j * 16 + (lane & 15);
                C[(size_t)row * NCOLS + col] = acc[i][j][r];
            }
}

// ---------------------------------------------------------------------------
// Kernel 4: gate transform, microtiled. Grid (N_NODES, 2); block handles 64 of
// the 128 outputs for one node. Single barrier; 4o x 4b register tile/thread.
// ohalf=0 -> z path (ZS = bf16(z*state)); ohalf=1 -> r path (Rbuf).
__global__ __launch_bounds__(256) void gate_transform_kernel(
    const float* __restrict__ E, const float* __restrict__ wp,
    const float* __restrict__ bp, const float* __restrict__ x,
    const float* __restrict__ state, const float* __restrict__ AG,
    unsigned short* __restrict__ ZS, float* __restrict__ Rbuf)
{
    const int n     = blockIdx.x;
    const int ohalf = blockIdx.y;
    const int tid   = threadIdx.x;

    __shared__ float Wl[KTOT * LP];    // W'[k'][o_local], pitch 68
    __shared__ float Il[KTOT * LP];    // IN[k'][b],       pitch 68
    __shared__ float bias_l[64];

    float en[D_EMB];
#pragma unroll
    for (int d = 0; d < D_EMB; ++d) en[d] = E[n * D_EMB + d];

    // W'[kp][o] = sum_d en[d] * wp[d][kp][ohalf*64+o]   (wp flat: [10][132][128])
    for (int idx = tid; idx < KTOT * 16; idx += 256) {
        const int kp = idx >> 4;
        const int o4 = (idx & 15) << 2;
        const float* wpp = wp + (size_t)kp * GOUT + ohalf * 64 + o4;
        float s0 = 0.f, s1 = 0.f, s2 = 0.f, s3 = 0.f;
#pragma unroll
        for (int d = 0; d < D_EMB; ++d) {
            const float4 v = *(const float4*)(wpp + (size_t)d * KTOT * GOUT);
            s0 += en[d] * v.x; s1 += en[d] * v.y;
            s2 += en[d] * v.z; s3 += en[d] * v.w;
        }
        *(float4*)&Wl[kp * LP + o4] = make_float4(s0, s1, s2, s3);
    }
    if (tid < 64) {
        float s = 0.f;
#pragma unroll
        for (int d = 0; d < D_EMB; ++d) s += en[d] * bp[d * GOUT + ohalf * 64 + tid];
        bias_l[tid] = s;
    }
    // IN[kp][b]: kp<2 -> x, kp<66 -> state, else AG
    for (int idx = tid; idx < KTOT * BATCH; idx += 256) {
        const int kp = idx % KTOT;
        const int b  = idx / KTOT;
        float v;
        if (kp >= CIN)      v = AG[(size_t)n * NCOLS + b * CP + (kp - CIN)];
        else if (kp >= DIN) v = state[((size_t)b * N_NODES + n) * DOUT + kp - DIN];
        else                v = x[((size_t)b * N_NODES + n) * DIN + kp];
        Il[kp * LP + b] = v;
    }
    __syncthreads();

    const int og = (tid & 15) << 2;   // o_local base (0..60)
    const int bg = (tid >> 4) << 2;   // b base      (0..60)

    float acc[4][4];
#pragma unroll
    for (int i = 0; i < 4; ++i)
#pragma unroll
        for (int j = 0; j < 4; ++j) acc[i][j] = 0.f;

    const float* Wb = Wl + og;
    const float* Ib = Il + bg;
#pragma unroll 4
    for (int kp = 0; kp < KTOT; ++kp) {
        const float4 wv = *(const float4*)(Wb + kp * LP);
        const float4 iv = *(const float4*)(Ib + kp * LP);
        const float wa[4] = {wv.x, wv.y, wv.z, wv.w};
        const float ia[4] = {iv.x, iv.y, iv.z, iv.w};
#pragma unroll
        for (int bi = 0; bi < 4; ++bi)
#pragma unroll
            for (int oi = 0; oi < 4; ++oi) acc[bi][oi] += ia[bi] * wa[oi];
    }

    if (ohalf == 0) {
#pragma unroll
        for (int bi = 0; bi < 4; ++bi) {
            const int b = bg + bi;
            const float4 st4 = *(const float4*)&state[((size_t)b * N_NODES + n) * DOUT + og];
            const float z0 = 1.f / (1.f + __expf(-(acc[bi][0] + bias_l[og + 0])));
            const float z1 = 1.f / (1.f + __expf(-(acc[bi][1] + bias_l[og + 1])));
            const float z2 = 1.f / (1.f + __expf(-(acc[bi][2] + bias_l[og + 2])));
            const float z3 = 1.f / (1.f + __expf(-(acc[bi][3] + bias_l[og + 3])));
            ushort4 zz;
            zz.x = f2bf_rn(z0 * st4.x); zz.y = f2bf_rn(z1 * st4.y);
            zz.z = f2bf_rn(z2 * st4.z); zz.w = f2bf_rn(z3 * st4.w);
            *(ushort4*)&ZS[((size_t)n * BATCH + b) * DOUT + og] = zz;
        }
    } else {
#pragma unroll
        for (int bi = 0; bi < 4; ++bi) {
            const int b = bg + bi;
            float4 rr;
            rr.x = 1.f / (1.f + __expf(-(acc[bi][0] + bias_l[og + 0])));
            rr.y = 1.f / (1.f + __expf(-(acc[bi][1] + bias_l[og + 1])));
            rr.z = 1.f / (1.f + __expf(-(acc[bi][2] + bias_l[og + 2])));
            rr.w = 1.f / (1.f + __expf(-(acc[bi][3] + bias_l[og + 3])));
            *(float4*)&Rbuf[((size_t)n * BATCH + b) * DOUT + og] = rr;
        }
    }
}

// ---------------------------------------------------------------------------
// Kernel 5: update transform + GRU output, microtiled. One block per node.
__global__ __launch_bounds__(256) void update_final_kernel(
    const float* __restrict__ E, const float* __restrict__ wp,
    const float* __restrict__ bp, const float* __restrict__ x,
    const unsigned short* __restrict__ ZS, const float* __restrict__ AG,
    const float* __restrict__ state, const float* __restrict__ Rbuf,
    float* __restrict__ out)
{
    const int n   = blockIdx.x;
    const int tid = threadIdx.x;

    __shared__ float Wl[KTOT * LP];
    __shared__ float Il[KTOT * LP];
    __shared__ float bias_l[64];

    float en[D_EMB];
#pragma unroll
    for (int d = 0; d < D_EMB; ++d) en[d] = E[n * D_EMB + d];

    // W'[kp][o] = sum_d en[d] * wp[d][kp][o]   (wp flat: [10][132][64])
    for (int idx = tid; idx < KTOT * 16; idx += 256) {
        const int kp = idx >> 4;
        const int o4 = (idx & 15) << 2;
        const float* wpp = wp + (size_t)kp * DOUT + o4;
        float s0 = 0.f, s1 = 0.f, s2 = 0.f, s3 = 0.f;
#pragma unroll
        for (int d = 0; d < D_EMB; ++d) {
            const float4 v = *(const float4*)(wpp + (size_t)d * KTOT * DOUT);
            s0 += en[d] * v.x; s1 += en[d] * v.y;
            s2 += en[d] * v.z; s3 += en[d] * v.w;
        }
        *(float4*)&Wl[kp * LP + o4] = make_float4(s0, s1, s2, s3);
    }
    if (tid < 64) {
        float s = 0.f;
#pragma unroll
        for (int d = 0; d < D_EMB; ++d) s += en[d] * bp[d * DOUT + tid];
        bias_l[tid] = s;
    }
    for (int idx = tid; idx < KTOT * BATCH; idx += 256) {
        const int kp = idx % KTOT;
        const int b  = idx / KTOT;
        float v;
        if (kp >= CIN)      v = AG[(size_t)n * NCOLS + b * CP + (kp - CIN)];
        else if (kp >= DIN) v = bf2f(ZS[((size_t)n * BATCH + b) * DOUT + kp - DIN]);
        else                v = x[((size_t)b * N_NODES + n) * DIN + kp];
        Il[kp * LP + b] = v;
    }
    __syncthreads();

    const int og = (tid & 15) << 2;
    const int bg = (tid >> 4) << 2;

    float acc[4][4];
#pragma unroll
    for (int i = 0; i < 4; ++i)
#pragma unroll
        for (int j = 0; j < 4; ++j) acc[i][j] = 0.f;

    const float* Wb = Wl + og;
    const float* Ib = Il + bg;
#pragma unroll 4
    for (int kp = 0; kp < KTOT; ++kp) {
        const float4 wv = *(const float4*)(Wb + kp * LP);
        const float4 iv = *(const float4*)(Ib + kp * LP);
        const float wa[4] = {wv.x, wv.y, wv.z, wv.w};
        const float ia[4] = {iv.x, iv.y, iv.z, iv.w};
#pragma unroll
        for (int bi = 0; bi < 4; ++bi)
#pragma unroll
            for (int oi = 0; oi < 4; ++oi) acc[bi][oi] += ia[bi] * wa[oi];
    }

#pragma unroll
    for (int bi = 0; bi < 4; ++bi) {
        const int b = bg + bi;
        const float4 r4  = *(const float4*)&Rbuf[((size_t)n * BATCH + b) * DOUT + og];
        const float4 st4 = *(const float4*)&state[((size_t)b * N_NODES + n) * DOUT + og];
        float4 h;
        h.x = r4.x * st4.x + (1.f - r4.x) * tanhf(acc[bi][0] + bias_l[og + 0]);
        h.y = r4.y * st4.y + (1.f - r4.y) * tanhf(acc[bi][1] + bias_l[og + 1]);
        h.z = r4.z * st4.z + (1.f - r4.z) * tanhf(acc[bi][2] + bias_l[og + 2]);
        h.w = r4.w * st4.w + (1.f - r4.w) * tanhf(acc[bi][3] + bias_l[og + 3]);
        *(float4*)&out[((size_t)b * N_NODES + n) * DOUT + og] = h;
    }
}

// ---------------------------------------------------------------------------
extern "C" void kernel_launch(void* const* d_in, const int* in_sizes, int n_in,
                              void* d_out, int out_size, void* d_ws, size_t ws_size,
                              hipStream_t stream)
{
    const float* x  = (const float*)d_in[0];
    const float* st = (const float*)d_in[1];
    const float* E  = (const float*)d_in[2];
    const float* gw = (const float*)d_in[3];
    const float* gb = (const float*)d_in[4];
    const float* uw = (const float*)d_in[5];
    const float* ub = (const float*)d_in[6];
    float* out = (float*)d_out;

    // workspace layout (~112.2 MB)
    unsigned short* S_hi = (unsigned short*)d_ws;                  // 2048*2048 bf16
    unsigned short* XT   = S_hi + (size_t)N_NODES * N_NODES;       // 4352*2048 bf16
    float* AG = (float*)(XT + (size_t)NCOLS * N_NODES);            // 2048*4352 f32
    unsigned short* ZS = (unsigned short*)(AG + (size_t)N_NODES * NCOLS); // 2048*64*64 bf16
    float* Rb = (float*)(ZS + (size_t)N_NODES * BATCH * DOUT);     // 2048*64*64 f32

    supports_kernel<<<N_NODES, 256, 0, stream>>>(E, S_hi);
    build_xt_kernel<<<dim3(N_NODES / 64, BATCH), 256, 0, stream>>>(x, st, ZS, 0, XT);
    gemm_mfma_kernel<<<dim3(NCOLS / 128, N_NODES / 128), 256, 0, stream>>>(S_hi, XT, AG);
    gate_transform_kernel<<<dim3(N_NODES, 2), 256, 0, stream>>>(E, gw, gb, x, st, AG, ZS, Rb);
    build_xt_kernel<<<dim3(N_NODES / 64, BATCH), 256, 0, stream>>>(x, st, ZS, 1, XT);
    gemm_mfma_kernel<<<dim3(NCOLS / 128, N_NODES / 128), 256, 0, stream>>>(S_hi, XT, AG);
    update_final_kernel<<<N_NODES, 256, 0, stream>>>(E, uw, ub, x, ZS, AG, st, Rb, out);
}

// Round 5
// 538.766 us; speedup vs baseline: 3.2414x; 1.0620x over previous
//
#include <hip/hip_runtime.h>
#include <math.h>

#define N_NODES 2048
#define BATCH   64
#define DIN     2
#define DOUT    64
#define CIN     66     // DIN + DOUT
#define CP      68     // padded channel count
#define D_EMB   10
#define GOUT    128    // gate output channels (2*DOUT)
#define NCOLS   (BATCH*CP)   // 4352, GEMM N dimension
#define MK      2048         // GEMM K
#define KTOT    132          // 2*CIN: flattened (k, i) contraction axis
#define KPAD    136          // wpT row pitch (float4 aligned, zero pad)

typedef __attribute__((ext_vector_type(8))) short bf16x8;
typedef __attribute__((ext_vector_type(8))) unsigned short u16x8;
typedef __attribute__((ext_vector_type(4))) float f32x4;

__device__ __forceinline__ unsigned short f2bf_rn(float f) {
    unsigned u = __builtin_bit_cast(unsigned, f);
    unsigned r = u + 0x7FFFu + ((u >> 16) & 1u);   // RNE
    return (unsigned short)(r >> 16);
}
__device__ __forceinline__ float bf2f(unsigned short h) {
    unsigned u = ((unsigned)h) << 16;
    return __builtin_bit_cast(float, u);
}

__device__ __forceinline__ void gload_lds16(const void* g, void* l) {
    __builtin_amdgcn_global_load_lds(
        (const __attribute__((address_space(1))) unsigned int*)g,
        (__attribute__((address_space(3))) unsigned int*)l, 16, 0, 0);
}

// Fragment-layout LDS address: tiles [strip][kt][row16][k32] bf16 (1 KB per
// (strip,kt)); XOR swizzle spreads the 64B rows across banks (2-way uniform).
__device__ __forceinline__ int frag_addr(int strip, int kt, int row, int slice) {
    const int byte = ((strip * 5 + kt) * 16 + row) * 64 + slice * 16;
    return byte ^ ((row & 7) << 4);
}

// ---------------------------------------------------------------------------
// Kernel 0: wpT[d][o][kp] = wp[d][kp][o], kp padded to 136 with zeros.
__global__ __launch_bounds__(256) void transpose_pool_kernel(
    const float* __restrict__ wp, float* __restrict__ wpT, int OC, int total)
{
    const int idx = blockIdx.x * 256 + threadIdx.x;
    if (idx >= total) return;
    const int kp   = idx % KPAD;
    const int rest = idx / KPAD;
    const int o    = rest % OC;
    const int d    = rest / OC;
    wpT[idx] = (kp < KTOT) ? wp[((size_t)d * KTOT + kp) * OC + o] : 0.f;
}

// ---------------------------------------------------------------------------
// Kernel 1: S[n,m] = softmax_m(relu(E[n,:].E[m,:])) emitted as bf16.
__global__ __launch_bounds__(256) void supports_kernel(
    const float* __restrict__ E, unsigned short* __restrict__ S_hi)
{
    const int n   = blockIdx.x;
    const int tid = threadIdx.x;

    float en[D_EMB];
#pragma unroll
    for (int d = 0; d < D_EMB; ++d) en[d] = E[n * D_EMB + d];

    float vals[8];
    float mx = -1e30f;
#pragma unroll
    for (int j = 0; j < 8; ++j) {
        const int m = tid + j * 256;
        float dot = 0.f;
#pragma unroll
        for (int d = 0; d < D_EMB; ++d) dot += en[d] * E[m * D_EMB + d];
        dot = fmaxf(dot, 0.f);
        vals[j] = dot;
        mx = fmaxf(mx, dot);
    }

    __shared__ float sred[4];
    for (int off = 32; off > 0; off >>= 1) mx = fmaxf(mx, __shfl_xor(mx, off));
    if ((tid & 63) == 0) sred[tid >> 6] = mx;
    __syncthreads();
    mx = fmaxf(fmaxf(sred[0], sred[1]), fmaxf(sred[2], sred[3]));

    float sum = 0.f;
#pragma unroll
    for (int j = 0; j < 8; ++j) { vals[j] = __expf(vals[j] - mx); sum += vals[j]; }

    __syncthreads();
    for (int off = 32; off > 0; off >>= 1) sum += __shfl_xor(sum, off);
    if ((tid & 63) == 0) sred[tid >> 6] = sum;
    __syncthreads();
    sum = sred[0] + sred[1] + sred[2] + sred[3];

    const float inv = 1.f / sum;
#pragma unroll
    for (int j = 0; j < 8; ++j)
        S_hi[(size_t)n * N_NODES + tid + j * 256] = f2bf_rn(vals[j] * inv);
}

// ---------------------------------------------------------------------------
// Kernel 2: build XT[j][m] (bf16), j = b*CP + c, c = concat(x, state|zs) padded.
__global__ __launch_bounds__(256) void build_xt_kernel(
    const float* __restrict__ x, const float* __restrict__ state,
    const unsigned short* __restrict__ zs, const int use_zs,
    unsigned short* __restrict__ XT)
{
    const int b   = blockIdx.y;
    const int m0  = blockIdx.x * 64;
    const int tid = threadIdx.x;
    __shared__ float T[64][69];   // +1 pad: conflict-free column reads

    {
        const int r = tid >> 2;
        const int q = (tid & 3) * 16;
        if (use_zs) {
            const u16x8 v0 = *(const u16x8*)&zs[((size_t)(m0 + r) * BATCH + b) * DOUT + q];
            const u16x8 v1 = *(const u16x8*)&zs[((size_t)(m0 + r) * BATCH + b) * DOUT + q + 8];
#pragma unroll
            for (int u = 0; u < 8; ++u) {
                T[r][DIN + q + u]     = bf2f(v0[u]);
                T[r][DIN + q + 8 + u] = bf2f(v1[u]);
            }
        } else {
#pragma unroll
            for (int u = 0; u < 4; ++u) {
                const float4 v = *(const float4*)&state[((size_t)b * N_NODES + m0 + r) * DOUT + q + u * 4];
                T[r][DIN + q + u * 4 + 0] = v.x;
                T[r][DIN + q + u * 4 + 1] = v.y;
                T[r][DIN + q + u * 4 + 2] = v.z;
                T[r][DIN + q + u * 4 + 3] = v.w;
            }
        }
    }
    if (tid < 128) {
        const int r = tid >> 1, c = tid & 1;
        T[r][c] = x[((size_t)b * N_NODES + m0 + r) * DIN + c];
        T[r][CIN + c] = 0.f;   // pad channels 66,67
    }
    __syncthreads();

    for (int idx = tid; idx < CP * 64; idx += 256) {
        const int c  = idx >> 6;
        const int mm = idx & 63;
        XT[((size_t)(b * CP + c)) * N_NODES + m0 + mm] = f2bf_rn(T[mm][c]);
    }
}

// ---------------------------------------------------------------------------
// Kernel 3: bf16 MFMA GEMM  C[M,NC] = A[M,K] * B[K,NC], XCD-bijective swizzle.
// Grid: 544 = 34(bn) x 16(bm) = 8 XCDs x 68.
__global__ __launch_bounds__(256) void gemm_mfma_kernel(
    const unsigned short* __restrict__ A,
    const unsigned short* __restrict__ BT, float* __restrict__ C)
{
    __shared__ __align__(16) unsigned short As[4096];  // 8 KB, fragment order
    __shared__ __align__(16) unsigned short Bs[4096];

    const int tid  = threadIdx.x;
    const int lane = tid & 63;
    const int w    = tid >> 6;
    const int wr   = w >> 1, wc = w & 1;

    // bijective XCD remap: 544 blocks = 8 * 68
    const int wg   = blockIdx.x;
    const int wgid = (wg & 7) * 68 + (wg >> 3);
    const int bn   = wgid % 34;
    const int bm   = wgid / 34;

    f32x4 acc[4][4];
#pragma unroll
    for (int i = 0; i < 4; ++i)
#pragma unroll
        for (int j = 0; j < 4; ++j) acc[i][j] = (f32x4){0.f, 0.f, 0.f, 0.f};

    const int srow = ((tid >> 6) << 4) + (tid & 15);
    const int scol = ((tid >> 4) & 3) * 8;
    const unsigned a_off0 = (unsigned)(bm * 128 + srow) * MK + scol;
    const unsigned a_off1 = a_off0 + 64u * MK;
    const unsigned b_off0 = (unsigned)(bn * 128 + srow) * MK + scol;
    const unsigned b_off1 = b_off0 + 64u * MK;

    unsigned short* asl0 = As + tid * 8;
    unsigned short* asl1 = As + 2048 + tid * 8;
    unsigned short* bsl0 = Bs + tid * 8;
    unsigned short* bsl1 = Bs + 2048 + tid * 8;

#pragma unroll 1
    for (int k0 = 0; k0 < MK; k0 += 32) {
        gload_lds16(A  + a_off0 + k0, asl0);
        gload_lds16(A  + a_off1 + k0, asl1);
        gload_lds16(BT + b_off0 + k0, bsl0);
        gload_lds16(BT + b_off1 + k0, bsl1);
        __syncthreads();   // drains vmcnt(0): tiles visible

        bf16x8 af[4], bf[4];
#pragma unroll
        for (int i = 0; i < 4; ++i)
            af[i] = *(const bf16x8*)(As + ((wr * 4 + i) * 64 + lane) * 8);
#pragma unroll
        for (int j = 0; j < 4; ++j)
            bf[j] = *(const bf16x8*)(Bs + ((wc * 4 + j) * 64 + lane) * 8);
#pragma unroll
        for (int i = 0; i < 4; ++i)
#pragma unroll
            for (int j = 0; j < 4; ++j)
                acc[i][j] = __builtin_amdgcn_mfma_f32_16x16x32_bf16(
                    af[i], bf[j], acc[i][j], 0, 0, 0);
        __syncthreads();
    }

    const int crow0 = bm * 128 + wr * 64;
    const int ccol0 = bn * 128 + wc * 64;
#pragma unroll
    for (int i = 0; i < 4; ++i)
#pragma unroll
        for (int j = 0; j < 4; ++j)
#pragma unroll
            for (int r = 0; r < 4; ++r) {
                const int row = crow0 + i * 16 + (lane >> 4) * 4 + r;
                const int col = ccol0 + j * 16 + (lane & 15);
                C[(size_t)row * NCOLS + col] = acc[i][j][r];
            }
}

// ---------------------------------------------------------------------------
// Kernel 4: gate transform via per-node MFMA. Grid (N_NODES, 2).
// OUT[64b x 64o] = IN[64b x 132k] * W'[132k x 64o] (+bias), W' = sum_d en*wpT.
// IN bf16 (hi); W' split hi+lo (2 MFMA passes). One barrier.
__global__ __launch_bounds__(256) void gate_mfma_kernel(
    const float* __restrict__ E, const float* __restrict__ wpT,
    const float* __restrict__ bp, const float* __restrict__ x,
    const float* __restrict__ state, const float* __restrict__ AG,
    unsigned short* __restrict__ ZS, float* __restrict__ Rbuf)
{
    const int n     = blockIdx.x;
    const int ohalf = blockIdx.y;
    const int tid   = threadIdx.x;

    __shared__ __align__(16) unsigned short INh[10240];  // 20 KB frag layout
    __shared__ __align__(16) unsigned short Whi[10240];
    __shared__ __align__(16) unsigned short Wlo[10240];
    __shared__ float bias_l[64];

    float en[D_EMB];
#pragma unroll
    for (int d = 0; d < D_EMB; ++d) en[d] = E[n * D_EMB + d];

    // ---- W'hi/lo staging (o-major slots: global reads coalesce over kp) ----
    for (int slot = tid; slot < 1280; slot += 256) {
        const int o = slot / 20, s = slot % 20;
        float v[8] = {0.f, 0.f, 0.f, 0.f, 0.f, 0.f, 0.f, 0.f};
        if (s < 17) {
            const float* p = wpT + ((size_t)(ohalf * 64 + o)) * KPAD + s * 8;
#pragma unroll
            for (int d = 0; d < D_EMB; ++d) {
                const float4 a = *(const float4*)(p + (size_t)d * GOUT * KPAD);
                const float4 b = *(const float4*)(p + (size_t)d * GOUT * KPAD + 4);
                v[0] += en[d] * a.x; v[1] += en[d] * a.y;
                v[2] += en[d] * a.z; v[3] += en[d] * a.w;
                v[4] += en[d] * b.x; v[5] += en[d] * b.y;
                v[6] += en[d] * b.z; v[7] += en[d] * b.w;
            }
        }
        u16x8 hv, lv;
#pragma unroll
        for (int u = 0; u < 8; ++u) {
            const unsigned short h = f2bf_rn(v[u]);
            hv[u] = h;
            lv[u] = f2bf_rn(v[u] - bf2f(h));
        }
        const int addr = frag_addr(o >> 4, s >> 2, o & 15, s & 3);
        *(u16x8*)((char*)Whi + addr) = hv;
        *(u16x8*)((char*)Wlo + addr) = lv;
    }
    if (tid < 64) {
        float s = 0.f;
#pragma unroll
        for (int d = 0; d < D_EMB; ++d) s += en[d] * bp[d * GOUT + ohalf * 64 + tid];
        bias_l[tid] = s;
    }
    // ---- IN staging (b-major slots: k-contiguous sources) ----
    for (int slot = tid; slot < 1280; slot += 256) {
        const int b = slot / 20, s = slot % 20;
        u16x8 hv;
#pragma unroll
        for (int u = 0; u < 8; ++u) {
            const int k = s * 8 + u;
            float v;
            if (k < DIN)       v = x[((size_t)b * N_NODES + n) * DIN + k];
            else if (k < CIN)  v = state[((size_t)b * N_NODES + n) * DOUT + k - DIN];
            else if (k < KTOT) v = AG[(size_t)n * NCOLS + b * CP + (k - CIN)];
            else               v = 0.f;
            hv[u] = f2bf_rn(v);
        }
        *(u16x8*)((char*)INh + frag_addr(b >> 4, s >> 2, b & 15, s & 3)) = hv;
    }
    __syncthreads();

    // ---- MFMA: wave w owns b-strip w (16 rows) x 64 o ----
    const int lane = tid & 63, w = tid >> 6;
    const int row = lane & 15, sl = lane >> 4;

    bf16x8 af[5];
#pragma unroll
    for (int kt = 0; kt < 5; ++kt)
        af[kt] = *(const bf16x8*)((const char*)INh + frag_addr(w, kt, row, sl));

    f32x4 acc[4];
#pragma unroll
    for (int j = 0; j < 4; ++j) acc[j] = (f32x4){0.f, 0.f, 0.f, 0.f};

#pragma unroll
    for (int j = 0; j < 4; ++j) {
#pragma unroll
        for (int kt = 0; kt < 5; ++kt) {
            const bf16x8 bh = *(const bf16x8*)((const char*)Whi + frag_addr(j, kt, row, sl));
            acc[j] = __builtin_amdgcn_mfma_f32_16x16x32_bf16(af[kt], bh, acc[j], 0, 0, 0);
        }
#pragma unroll
        for (int kt = 0; kt < 5; ++kt) {
            const bf16x8 bl = *(const bf16x8*)((const char*)Wlo + frag_addr(j, kt, row, sl));
            acc[j] = __builtin_amdgcn_mfma_f32_16x16x32_bf16(af[kt], bl, acc[j], 0, 0, 0);
        }
    }

    // ---- epilogue ----
#pragma unroll
    for (int j = 0; j < 4; ++j) {
        const int ol = j * 16 + row;           // o within this half
        const float bs = bias_l[ol];
#pragma unroll
        for (int r = 0; r < 4; ++r) {
            const int b = w * 16 + sl * 4 + r;
            const float sg = 1.f / (1.f + __expf(-(acc[j][r] + bs)));
            if (ohalf == 0) {
                ZS[((size_t)n * BATCH + b) * DOUT + ol] =
                    f2bf_rn(sg * state[((size_t)b * N_NODES + n) * DOUT + ol]);
            } else {
                Rbuf[((size_t)n * BATCH + b) * DOUT + ol] = sg;
            }
        }
    }
}

// ---------------------------------------------------------------------------
// Kernel 5: update transform + GRU output via per-node MFMA. Grid N_NODES.
__global__ __launch_bounds__(256) void update_mfma_kernel(
    const float* __restrict__ E, const float* __restrict__ wpT,
    const float* __restrict__ bp, const float* __restrict__ x,
    const unsigned short* __restrict__ ZS, const float* __restrict__ AG,
    const float* __restrict__ state, const float* __restrict__ Rbuf,
    float* __restrict__ out)
{
    const int n   = blockIdx.x;
    const int tid = threadIdx.x;

    __shared__ __align__(16) unsigned short INh[10240];
    __shared__ __align__(16) unsigned short Whi[10240];
    __shared__ __align__(16) unsigned short Wlo[10240];
    __shared__ float bias_l[64];

    float en[D_EMB];
#pragma unroll
    for (int d = 0; d < D_EMB; ++d) en[d] = E[n * D_EMB + d];

    for (int slot = tid; slot < 1280; slot += 256) {
        const int o = slot / 20, s = slot % 20;
        float v[8] = {0.f, 0.f, 0.f, 0.f, 0.f, 0.f, 0.f, 0.f};
        if (s < 17) {
            const float* p = wpT + (size_t)o * KPAD + s * 8;
#pragma unroll
            for (int d = 0; d < D_EMB; ++d) {
                const float4 a = *(const float4*)(p + (size_t)d * DOUT * KPAD);
                const float4 b = *(const float4*)(p + (size_t)d * DOUT * KPAD + 4);
                v[0] += en[d] * a.x; v[1] += en[d] * a.y;
                v[2] += en[d] * a.z; v[3] += en[d] * a.w;
                v[4] += en[d] * b.x; v[5] += en[d] * b.y;
                v[6] += en[d] * b.z; v[7] += en[d] * b.w;
            }
        }
        u16x8 hv, lv;
#pragma unroll
        for (int u = 0; u < 8; ++u) {
            const unsigned short h = f2bf_rn(v[u]);
            hv[u] = h;
            lv[u] = f2bf_rn(v[u] - bf2f(h));
        }
        const int addr = frag_addr(o >> 4, s >> 2, o & 15, s & 3);
        *(u16x8*)((char*)Whi + addr) = hv;
        *(u16x8*)((char*)Wlo + addr) = lv;
    }
    if (tid < 64) {
        float s = 0.f;
#pragma unroll
        for (int d = 0; d < D_EMB; ++d) s += en[d] * bp[d * DOUT + tid];
        bias_l[tid] = s;
    }
    for (int slot = tid; slot < 1280; slot += 256) {
        const int b = slot / 20, s = slot % 20;
        u16x8 hv;
#pragma unroll
        for (int u = 0; u < 8; ++u) {
            const int k = s * 8 + u;
            float v;
            if (k < DIN)       v = x[((size_t)b * N_NODES + n) * DIN + k];
            else if (k < CIN)  v = bf2f(ZS[((size_t)n * BATCH + b) * DOUT + k - DIN]);
            else if (k < KTOT) v = AG[(size_t)n * NCOLS + b * CP + (k - CIN)];
            else               v = 0.f;
            hv[u] = f2bf_rn(v);
        }
        *(u16x8*)((char*)INh + frag_addr(b >> 4, s >> 2, b & 15, s & 3)) = hv;
    }
    __syncthreads();

    const int lane = tid & 63, w = tid >> 6;
    const int row = lane & 15, sl = lane >> 4;

    bf16x8 af[5];
#pragma unroll
    for (int kt = 0; kt < 5; ++kt)
        af[kt] = *(const bf16x8*)((const char*)INh + frag_addr(w, kt, row, sl));

    f32x4 acc[4];
#pragma unroll
    for (int j = 0; j < 4; ++j) acc[j] = (f32x4){0.f, 0.f, 0.f, 0.f};

#pragma unroll
    for (int j = 0; j < 4; ++j) {
#pragma unroll
        for (int kt = 0; kt < 5; ++kt) {
            const bf16x8 bh = *(const bf16x8*)((const char*)Whi + frag_addr(j, kt, row, sl));
            acc[j] = __builtin_amdgcn_mfma_f32_16x16x32_bf16(af[kt], bh, acc[j], 0, 0, 0);
        }
#pragma unroll
        for (int kt = 0; kt < 5; ++kt) {
            const bf16x8 bl = *(const bf16x8*)((const char*)Wlo + frag_addr(j, kt, row, sl));
            acc[j] = __builtin_amdgcn_mfma_f32_16x16x32_bf16(af[kt], bl, acc[j], 0, 0, 0);
        }
    }

#pragma unroll
    for (int j = 0; j < 4; ++j) {
        const int ol = j * 16 + row;
        const float bs = bias_l[ol];
#pragma unroll
        for (int r = 0; r < 4; ++r) {
            const int b = w * 16 + sl * 4 + r;
            const float hc = tanhf(acc[j][r] + bs);
            const float rr = Rbuf[((size_t)n * BATCH + b) * DOUT + ol];
            const float st = state[((size_t)b * N_NODES + n) * DOUT + ol];
            out[((size_t)b * N_NODES + n) * DOUT + ol] = rr * st + (1.f - rr) * hc;
        }
    }
}

// ---------------------------------------------------------------------------
extern "C" void kernel_launch(void* const* d_in, const int* in_sizes, int n_in,
                              void* d_out, int out_size, void* d_ws, size_t ws_size,
                              hipStream_t stream)
{
    const float* x  = (const float*)d_in[0];
    const float* st = (const float*)d_in[1];
    const float* E  = (const float*)d_in[2];
    const float* gw = (const float*)d_in[3];
    const float* gb = (const float*)d_in[4];
    const float* uw = (const float*)d_in[5];
    const float* ub = (const float*)d_in[6];
    float* out = (float*)d_out;

    // workspace layout (~113.3 MB)
    unsigned short* S_hi = (unsigned short*)d_ws;                  // 2048*2048 bf16
    unsigned short* XT   = S_hi + (size_t)N_NODES * N_NODES;       // 4352*2048 bf16
    float* AG = (float*)(XT + (size_t)NCOLS * N_NODES);            // 2048*4352 f32
    unsigned short* ZS = (unsigned short*)(AG + (size_t)N_NODES * NCOLS); // 2048*64*64 bf16
    float* Rb   = (float*)(ZS + (size_t)N_NODES * BATCH * DOUT);   // 2048*64*64 f32
    float* wpTg = Rb + (size_t)N_NODES * BATCH * DOUT;             // 10*128*136 f32
    float* wpTu = wpTg + (size_t)D_EMB * GOUT * KPAD;              // 10*64*136 f32

    const int tg = D_EMB * GOUT * KPAD;   // 174080
    const int tu = D_EMB * DOUT * KPAD;   // 87040
    transpose_pool_kernel<<<(tg + 255) / 256, 256, 0, stream>>>(gw, wpTg, GOUT, tg);
    transpose_pool_kernel<<<(tu + 255) / 256, 256, 0, stream>>>(uw, wpTu, DOUT, tu);

    supports_kernel<<<N_NODES, 256, 0, stream>>>(E, S_hi);
    build_xt_kernel<<<dim3(N_NODES / 64, BATCH), 256, 0, stream>>>(x, st, ZS, 0, XT);
    gemm_mfma_kernel<<<544, 256, 0, stream>>>(S_hi, XT, AG);
    gate_mfma_kernel<<<dim3(N_NODES, 2), 256, 0, stream>>>(E, wpTg, gb, x, st, AG, ZS, Rb);
    build_xt_kernel<<<dim3(N_NODES / 64, BATCH), 256, 0, stream>>>(x, st, ZS, 1, XT);
    gemm_mfma_kernel<<<544, 256, 0, stream>>>(S_hi, XT, AG);
    update_mfma_kernel<<<N_NODES, 256, 0, stream>>>(E, wpTu, ub, x, ZS, AG, st, Rb, out);
}

// Round 6
// 485.421 us; speedup vs baseline: 3.5977x; 1.1099x over previous
//
#include <hip/hip_runtime.h>
#include <math.h>

#define N_NODES 2048
#define BATCH   64
#define DIN     2
#define DOUT    64
#define CIN     66     // DIN + DOUT
#define CP      68     // padded channel count (GEMM col blocking)
#define D_EMB   10
#define GOUT    128    // gate output channels (2*DOUT)
#define NCOLS   (BATCH*CP)   // 4352, GEMM N dimension
#define MK      2048         // GEMM K
#define KPAD    136          // wpT row pitch
#define INP     160          // IN row pitch (bf16 elems): [0,1]=unused [2,65]=zs [66,133]=AG [134,159]=0
#define WHALF   20480        // bytes per hi (or lo) fragment half-blob (64o x 160k bf16)
#define WBLOB   40960        // hi+lo per (node, o-half)

typedef __attribute__((ext_vector_type(8))) short bf16x8;
typedef __attribute__((ext_vector_type(8))) unsigned short u16x8;
typedef __attribute__((ext_vector_type(4))) float f32x4;

__device__ __forceinline__ unsigned short f2bf_rn(float f) {
    unsigned u = __builtin_bit_cast(unsigned, f);
    unsigned r = u + 0x7FFFu + ((u >> 16) & 1u);   // RNE
    return (unsigned short)(r >> 16);
}
__device__ __forceinline__ float bf2f(unsigned short h) {
    unsigned u = ((unsigned)h) << 16;
    return __builtin_bit_cast(float, u);
}

__device__ __forceinline__ void gload_lds16(const void* g, void* l) {
    __builtin_amdgcn_global_load_lds(
        (const __attribute__((address_space(1))) unsigned int*)g,
        (__attribute__((address_space(3))) unsigned int*)l, 16, 0, 0);
}

// Fragment-layout address inside a 20 KB half-blob: [strip4][kt5][row16][sl4]x16B,
// XOR swizzle spreads the 64B rows across banks (uniform 2-way on b128 reads).
__device__ __forceinline__ int frag_addr(int strip, int kt, int row, int slice) {
    const int byte = ((strip * 5 + kt) * 16 + row) * 64 + slice * 16;
    return byte ^ ((row & 7) << 4);
}

// ---------------------------------------------------------------------------
// Kernel 0: wpT[d][o][kp] = wp[d][kp][o], kp padded to 136 with zeros.
__global__ __launch_bounds__(256) void transpose_pool_kernel(
    const float* __restrict__ wp, float* __restrict__ wpT, int OC, int total)
{
    const int idx = blockIdx.x * 256 + threadIdx.x;
    if (idx >= total) return;
    const int kp   = idx % KPAD;
    const int rest = idx / KPAD;
    const int o    = rest % OC;
    const int d    = rest / OC;
    wpT[idx] = (kp < 132) ? wp[((size_t)d * 132 + kp) * OC + o] : 0.f;
}

// ---------------------------------------------------------------------------
// Kernel 1: S[n,m] = softmax_m(relu(E[n,:].E[m,:])) emitted as bf16.
__global__ __launch_bounds__(256) void supports_kernel(
    const float* __restrict__ E, unsigned short* __restrict__ S_hi)
{
    const int n   = blockIdx.x;
    const int tid = threadIdx.x;

    float en[D_EMB];
#pragma unroll
    for (int d = 0; d < D_EMB; ++d) en[d] = E[n * D_EMB + d];

    float vals[8];
    float mx = -1e30f;
#pragma unroll
    for (int j = 0; j < 8; ++j) {
        const int m = tid + j * 256;
        float dot = 0.f;
#pragma unroll
        for (int d = 0; d < D_EMB; ++d) dot += en[d] * E[m * D_EMB + d];
        dot = fmaxf(dot, 0.f);
        vals[j] = dot;
        mx = fmaxf(mx, dot);
    }

    __shared__ float sred[4];
    for (int off = 32; off > 0; off >>= 1) mx = fmaxf(mx, __shfl_xor(mx, off));
    if ((tid & 63) == 0) sred[tid >> 6] = mx;
    __syncthreads();
    mx = fmaxf(fmaxf(sred[0], sred[1]), fmaxf(sred[2], sred[3]));

    float sum = 0.f;
#pragma unroll
    for (int j = 0; j < 8; ++j) { vals[j] = __expf(vals[j] - mx); sum += vals[j]; }

    __syncthreads();
    for (int off = 32; off > 0; off >>= 1) sum += __shfl_xor(sum, off);
    if ((tid & 63) == 0) sred[tid >> 6] = sum;
    __syncthreads();
    sum = sred[0] + sred[1] + sred[2] + sred[3];

    const float inv = 1.f / sum;
#pragma unroll
    for (int j = 0; j < 8; ++j)
        S_hi[(size_t)n * N_NODES + tid + j * 256] = f2bf_rn(vals[j] * inv);
}

// ---------------------------------------------------------------------------
// Kernel 2: zero IN[:, :, 134..159] (ws is re-poisoned before every call).
__global__ __launch_bounds__(256) void zero_tail_kernel(unsigned short* __restrict__ IN)
{
    const int idx = blockIdx.x * 256 + threadIdx.x;   // rows * 13 dwords
    if (idx >= N_NODES * BATCH * 13) return;
    const int row = idx / 13, j = idx % 13;
    *(unsigned int*)((char*)IN + (size_t)row * INP * 2 + 268 + j * 4) = 0u;
}

// ---------------------------------------------------------------------------
// Kernel 3: build XT[col=b*CP+c][m] bf16 for the GEMM B operand.
// pass 0: channels from x/state(f32); pass 1: channels from x/IN-zs(bf16).
__global__ __launch_bounds__(256) void build_xt_kernel(
    const float* __restrict__ x, const float* __restrict__ state,
    const unsigned short* __restrict__ INz, const int use_zs,
    unsigned short* __restrict__ XT)
{
    const int b   = blockIdx.y;
    const int m0  = blockIdx.x * 64;
    const int tid = threadIdx.x;
    __shared__ float T[64][69];   // +1 pad: conflict-free column reads

    {
        const int r = tid >> 2;
        const int q = (tid & 3) * 16;
        if (use_zs) {
            const unsigned int* p = (const unsigned int*)
                ((const char*)INz + (((size_t)(m0 + r) * BATCH + b) * INP + 2 + q) * 2);
#pragma unroll
            for (int t = 0; t < 8; ++t) {
                const unsigned int v = p[t];
                T[r][DIN + q + 2 * t]     = bf2f((unsigned short)(v & 0xFFFFu));
                T[r][DIN + q + 2 * t + 1] = bf2f((unsigned short)(v >> 16));
            }
        } else {
#pragma unroll
            for (int u = 0; u < 4; ++u) {
                const float4 v = *(const float4*)&state[((size_t)b * N_NODES + m0 + r) * DOUT + q + u * 4];
                T[r][DIN + q + u * 4 + 0] = v.x;
                T[r][DIN + q + u * 4 + 1] = v.y;
                T[r][DIN + q + u * 4 + 2] = v.z;
                T[r][DIN + q + u * 4 + 3] = v.w;
            }
        }
    }
    if (tid < 128) {
        const int r = tid >> 1, c = tid & 1;
        T[r][c] = x[((size_t)b * N_NODES + m0 + r) * DIN + c];
        T[r][CIN + c] = 0.f;   // pad channels 66,67
    }
    __syncthreads();

    for (int idx = tid; idx < CP * 64; idx += 256) {
        const int c  = idx >> 6;
        const int mm = idx & 63;
        XT[((size_t)(b * CP + c)) * N_NODES + m0 + mm] = f2bf_rn(T[mm][c]);
    }
}

// ---------------------------------------------------------------------------
// Kernel 4: bf16 MFMA GEMM; epilogue writes bf16 into IN[n][b][66+c].
__global__ __launch_bounds__(256) void gemm_mfma_kernel(
    const unsigned short* __restrict__ A,
    const unsigned short* __restrict__ BT, unsigned short* __restrict__ INout)
{
    __shared__ __align__(16) unsigned short As[4096];
    __shared__ __align__(16) unsigned short Bs[4096];

    const int tid  = threadIdx.x;
    const int lane = tid & 63;
    const int w    = tid >> 6;
    const int wr   = w >> 1, wc = w & 1;

    // bijective XCD remap: 544 blocks = 8 * 68
    const int wg   = blockIdx.x;
    const int wgid = (wg & 7) * 68 + (wg >> 3);
    const int bn   = wgid % 34;
    const int bm   = wgid / 34;

    f32x4 acc[4][4];
#pragma unroll
    for (int i = 0; i < 4; ++i)
#pragma unroll
        for (int j = 0; j < 4; ++j) acc[i][j] = (f32x4){0.f, 0.f, 0.f, 0.f};

    const int srow = ((tid >> 6) << 4) + (tid & 15);
    const int scol = ((tid >> 4) & 3) * 8;
    const unsigned a_off0 = (unsigned)(bm * 128 + srow) * MK + scol;
    const unsigned a_off1 = a_off0 + 64u * MK;
    const unsigned b_off0 = (unsigned)(bn * 128 + srow) * MK + scol;
    const unsigned b_off1 = b_off0 + 64u * MK;

    unsigned short* asl0 = As + tid * 8;
    unsigned short* asl1 = As + 2048 + tid * 8;
    unsigned short* bsl0 = Bs + tid * 8;
    unsigned short* bsl1 = Bs + 2048 + tid * 8;

#pragma unroll 1
    for (int k0 = 0; k0 < MK; k0 += 32) {
        gload_lds16(A  + a_off0 + k0, asl0);
        gload_lds16(A  + a_off1 + k0, asl1);
        gload_lds16(BT + b_off0 + k0, bsl0);
        gload_lds16(BT + b_off1 + k0, bsl1);
        __syncthreads();

        bf16x8 af[4], bf[4];
#pragma unroll
        for (int i = 0; i < 4; ++i)
            af[i] = *(const bf16x8*)(As + ((wr * 4 + i) * 64 + lane) * 8);
#pragma unroll
        for (int j = 0; j < 4; ++j)
            bf[j] = *(const bf16x8*)(Bs + ((wc * 4 + j) * 64 + lane) * 8);
#pragma unroll
        for (int i = 0; i < 4; ++i)
#pragma unroll
            for (int j = 0; j < 4; ++j)
                acc[i][j] = __builtin_amdgcn_mfma_f32_16x16x32_bf16(
                    af[i], bf[j], acc[i][j], 0, 0, 0);
        __syncthreads();
    }

    const int crow0 = bm * 128 + wr * 64;
    const int ccol0 = bn * 128 + wc * 64;
#pragma unroll
    for (int j = 0; j < 4; ++j) {
        const int col = ccol0 + j * 16 + (lane & 15);
        const int b   = col / 68;
        const int c   = col - b * 68;
#pragma unroll
        for (int i = 0; i < 4; ++i)
#pragma unroll
            for (int r = 0; r < 4; ++r) {
                const int row = crow0 + i * 16 + (lane >> 4) * 4 + r;   // = n
                INout[((size_t)row * BATCH + b) * INP + 66 + c] = f2bf_rn(acc[i][j][r]);
            }
    }
}

// ---------------------------------------------------------------------------
// Kernel 5: weight precompute. Writes per-node blobs in fragment order:
// blob(node) = [half NH][hi 20KB][lo 20KB]; addr = frag_addr (pre-swizzled).
// grid: (NH*1280/256, nN/16); thread = one (half,o,s) column x 16 nodes.
__global__ __launch_bounds__(256) void wgen_kernel(
    const float* __restrict__ E, const float* __restrict__ wpT,
    unsigned char* __restrict__ Wc, int n0, int NH, int OC)
{
    const int tid  = threadIdx.x;
    const int cid  = blockIdx.x * 256 + tid;   // exact: NH*1280 total
    const int half = cid / 1280;
    const int rest = cid % 1280;
    const int o_l  = rest / 20;
    const int s    = rest % 20;
    const int o_g  = half * 64 + o_l;

    __shared__ float en_s[16][D_EMB];
    if (tid < 16 * D_EMB) {
        const int i = tid / D_EMB, d = tid % D_EMB;
        en_s[i][d] = E[(n0 + blockIdx.y * 16 + i) * D_EMB + d];
    }

    float wv[D_EMB][8];
    if (s < 17) {
        const float* p = wpT + (size_t)o_g * KPAD + s * 8;
#pragma unroll
        for (int d = 0; d < D_EMB; ++d) {
            const float4 a = *(const float4*)(p + (size_t)d * OC * KPAD);
            const float4 b = *(const float4*)(p + (size_t)d * OC * KPAD + 4);
            wv[d][0] = a.x; wv[d][1] = a.y; wv[d][2] = a.z; wv[d][3] = a.w;
            wv[d][4] = b.x; wv[d][5] = b.y; wv[d][6] = b.z; wv[d][7] = b.w;
        }
    } else {
#pragma unroll
        for (int d = 0; d < D_EMB; ++d)
#pragma unroll
            for (int u = 0; u < 8; ++u) wv[d][u] = 0.f;
    }
    __syncthreads();

    const int addr = frag_addr(o_l >> 4, s >> 2, o_l & 15, s & 3);
    unsigned char* base0 = Wc + (size_t)blockIdx.y * 16 * NH * WBLOB + (size_t)half * WBLOB;
#pragma unroll 1
    for (int i = 0; i < 16; ++i) {
        float v[8] = {0.f, 0.f, 0.f, 0.f, 0.f, 0.f, 0.f, 0.f};
#pragma unroll
        for (int d = 0; d < D_EMB; ++d) {
            const float e = en_s[i][d];
#pragma unroll
            for (int u = 0; u < 8; ++u) v[u] += e * wv[d][u];
        }
        u16x8 hv, lv;
#pragma unroll
        for (int u = 0; u < 8; ++u) {
            const unsigned short h = f2bf_rn(v[u]);
            hv[u] = h;
            lv[u] = f2bf_rn(v[u] - bf2f(h));
        }
        unsigned char* nb = base0 + (size_t)i * NH * WBLOB;
        *(u16x8*)(nb + addr)         = hv;
        *(u16x8*)(nb + WHALF + addr) = lv;
    }
}

// ---------------------------------------------------------------------------
// A-fragment helpers (register-direct, no LDS)
union afrag { u16x8 u; bf16x8 s; };

// ---------------------------------------------------------------------------
// Kernel 6: gate transform. Grid (nN, 2). Stages 40 KB W blob linearly via
// global_load_lds; A-frags direct from x/state(f32) + IN-AG(bf16).
// half0 -> zs=bf16(sigmoid*state) into IN[2..65]; half1 -> r into Rb (bf16).
__global__ __launch_bounds__(256) void gate_mfma_kernel(
    const float* __restrict__ E, const float* __restrict__ bp,
    const float* __restrict__ x, const float* __restrict__ state,
    unsigned short* __restrict__ IN, const unsigned char* __restrict__ Wc,
    int n0, unsigned short* __restrict__ Rb)
{
    const int n_l  = blockIdx.x;
    const int n    = n0 + n_l;
    const int half = blockIdx.y;
    const int tid  = threadIdx.x;

    __shared__ __align__(16) unsigned char Ws[WBLOB];
    __shared__ float bias_l[64];

    const unsigned char* src = Wc + (size_t)n_l * (2 * WBLOB) + (size_t)half * WBLOB;
#pragma unroll
    for (int i = 0; i < 10; ++i)
        gload_lds16(src + (tid + i * 256) * 16, Ws + (tid + i * 256) * 16);

    if (tid < 64) {
        float s = 0.f;
#pragma unroll
        for (int d = 0; d < D_EMB; ++d)
            s += E[n * D_EMB + d] * bp[d * GOUT + half * 64 + tid];
        bias_l[tid] = s;
    }

    const int lane = tid & 63, w = tid >> 6;
    const int row = lane & 15, sl = lane >> 4;
    const int b = w * 16 + row;
    const float* stp = state + ((size_t)b * N_NODES + n) * DOUT;
    const float2 xv  = *(const float2*)(x + ((size_t)b * N_NODES + n) * DIN);
    const unsigned short* inr = IN + ((size_t)n * BATCH + b) * INP;

    afrag af[5];
    {   // kt0: k 0..31 -> x + state c0..29
        float f[8];
        if (sl == 0) {
            f[0] = xv.x; f[1] = xv.y;
            const float2 s0 = *(const float2*)(stp + 0);
            const float2 s1 = *(const float2*)(stp + 2);
            const float2 s2 = *(const float2*)(stp + 4);
            f[2] = s0.x; f[3] = s0.y; f[4] = s1.x; f[5] = s1.y; f[6] = s2.x; f[7] = s2.y;
        } else {
            const float* sp = stp + sl * 8 - 2;
#pragma unroll
            for (int t = 0; t < 4; ++t) {
                const float2 v = *(const float2*)(sp + 2 * t);
                f[2 * t] = v.x; f[2 * t + 1] = v.y;
            }
        }
#pragma unroll
        for (int u = 0; u < 8; ++u) af[0].u[u] = f2bf_rn(f[u]);
    }
    {   // kt1: k 32..63 -> state c30..61
        const float* sp = stp + 30 + sl * 8;
        float f[8];
#pragma unroll
        for (int t = 0; t < 4; ++t) {
            const float2 v = *(const float2*)(sp + 2 * t);
            f[2 * t] = v.x; f[2 * t + 1] = v.y;
        }
#pragma unroll
        for (int u = 0; u < 8; ++u) af[1].u[u] = f2bf_rn(f[u]);
    }
    if (sl == 0) {   // kt2 sl0: state c62,63 + IN k66..71
        af[2].u[0] = f2bf_rn(stp[62]);
        af[2].u[1] = f2bf_rn(stp[63]);
        const unsigned int* q = (const unsigned int*)((const char*)inr + 132);
        const unsigned int q0 = q[0], q1 = q[1], q2 = q[2];
        af[2].u[2] = (unsigned short)q0; af[2].u[3] = (unsigned short)(q0 >> 16);
        af[2].u[4] = (unsigned short)q1; af[2].u[5] = (unsigned short)(q1 >> 16);
        af[2].u[6] = (unsigned short)q2; af[2].u[7] = (unsigned short)(q2 >> 16);
    } else {
        af[2].u = *(const u16x8*)(inr + 64 + sl * 8);
    }
    af[3].u = *(const u16x8*)(inr + 96 + sl * 8);
    af[4].u = *(const u16x8*)(inr + 128 + sl * 8);

    __syncthreads();   // W blob + bias visible

    f32x4 acc[4];
#pragma unroll
    for (int j = 0; j < 4; ++j) acc[j] = (f32x4){0.f, 0.f, 0.f, 0.f};
#pragma unroll
    for (int j = 0; j < 4; ++j) {
#pragma unroll
        for (int kt = 0; kt < 5; ++kt) {
            const bf16x8 bh = *(const bf16x8*)(Ws + frag_addr(j, kt, row, sl));
            acc[j] = __builtin_amdgcn_mfma_f32_16x16x32_bf16(af[kt].s, bh, acc[j], 0, 0, 0);
        }
#pragma unroll
        for (int kt = 0; kt < 5; ++kt) {
            const bf16x8 bl = *(const bf16x8*)(Ws + WHALF + frag_addr(j, kt, row, sl));
            acc[j] = __builtin_amdgcn_mfma_f32_16x16x32_bf16(af[kt].s, bl, acc[j], 0, 0, 0);
        }
    }

#pragma unroll
    for (int j = 0; j < 4; ++j) {
        const int o_l = j * 16 + row;
        const float bs = bias_l[o_l];
#pragma unroll
        for (int r = 0; r < 4; ++r) {
            const int bb = w * 16 + sl * 4 + r;
            const float sg = 1.f / (1.f + __expf(-(acc[j][r] + bs)));
            if (half == 0) {
                const float st = state[((size_t)bb * N_NODES + n) * DOUT + o_l];
                IN[((size_t)n * BATCH + bb) * INP + 2 + o_l] = f2bf_rn(sg * st);
            } else {
                Rb[((size_t)n * BATCH + bb) * DOUT + o_l] = f2bf_rn(sg);
            }
        }
    }
}

// ---------------------------------------------------------------------------
// Kernel 7: update transform + GRU output. Grid nN.
__global__ __launch_bounds__(256) void update_mfma_kernel(
    const float* __restrict__ E, const float* __restrict__ bp,
    const float* __restrict__ x, const float* __restrict__ state,
    const unsigned short* __restrict__ IN, const unsigned char* __restrict__ Wc,
    int n0, const unsigned short* __restrict__ Rb, float* __restrict__ out)
{
    const int n_l = blockIdx.x;
    const int n   = n0 + n_l;
    const int tid = threadIdx.x;

    __shared__ __align__(16) unsigned char Ws[WBLOB];
    __shared__ float bias_l[64];

    const unsigned char* src = Wc + (size_t)n_l * WBLOB;
#pragma unroll
    for (int i = 0; i < 10; ++i)
        gload_lds16(src + (tid + i * 256) * 16, Ws + (tid + i * 256) * 16);

    if (tid < 64) {
        float s = 0.f;
#pragma unroll
        for (int d = 0; d < D_EMB; ++d)
            s += E[n * D_EMB + d] * bp[d * DOUT + tid];
        bias_l[tid] = s;
    }

    const int lane = tid & 63, w = tid >> 6;
    const int row = lane & 15, sl = lane >> 4;
    const int b = w * 16 + row;
    const unsigned short* inr = IN + ((size_t)n * BATCH + b) * INP;

    afrag af[5];
    if (sl == 0) {   // kt0 sl0: x + zs k2..7
        const float2 xv = *(const float2*)(x + ((size_t)b * N_NODES + n) * DIN);
        af[0].u[0] = f2bf_rn(xv.x);
        af[0].u[1] = f2bf_rn(xv.y);
        const unsigned int* q = (const unsigned int*)((const char*)inr + 4);
        const unsigned int q0 = q[0], q1 = q[1], q2 = q[2];
        af[0].u[2] = (unsigned short)q0; af[0].u[3] = (unsigned short)(q0 >> 16);
        af[0].u[4] = (unsigned short)q1; af[0].u[5] = (unsigned short)(q1 >> 16);
        af[0].u[6] = (unsigned short)q2; af[0].u[7] = (unsigned short)(q2 >> 16);
    } else {
        af[0].u = *(const u16x8*)(inr + sl * 8);
    }
#pragma unroll
    for (int kt = 1; kt < 5; ++kt)
        af[kt].u = *(const u16x8*)(inr + kt * 32 + sl * 8);

    __syncthreads();

    f32x4 acc[4];
#pragma unroll
    for (int j = 0; j < 4; ++j) acc[j] = (f32x4){0.f, 0.f, 0.f, 0.f};
#pragma unroll
    for (int j = 0; j < 4; ++j) {
#pragma unroll
        for (int kt = 0; kt < 5; ++kt) {
            const bf16x8 bh = *(const bf16x8*)(Ws + frag_addr(j, kt, row, sl));
            acc[j] = __builtin_amdgcn_mfma_f32_16x16x32_bf16(af[kt].s, bh, acc[j], 0, 0, 0);
        }
#pragma unroll
        for (int kt = 0; kt < 5; ++kt) {
            const bf16x8 bl = *(const bf16x8*)(Ws + WHALF + frag_addr(j, kt, row, sl));
            acc[j] = __builtin_amdgcn_mfma_f32_16x16x32_bf16(af[kt].s, bl, acc[j], 0, 0, 0);
        }
    }

#pragma unroll
    for (int j = 0; j < 4; ++j) {
        const int o_l = j * 16 + row;
        const float bs = bias_l[o_l];
#pragma unroll
        for (int r = 0; r < 4; ++r) {
            const int bb = w * 16 + sl * 4 + r;
            const float hc = tanhf(acc[j][r] + bs);
            const float rr = bf2f(Rb[((size_t)n * BATCH + bb) * DOUT + o_l]);
            const float st = state[((size_t)bb * N_NODES + n) * DOUT + o_l];
            out[((size_t)bb * N_NODES + n) * DOUT + o_l] = rr * st + (1.f - rr) * hc;
        }
    }
}

// ---------------------------------------------------------------------------
extern "C" void kernel_launch(void* const* d_in, const int* in_sizes, int n_in,
                              void* d_out, int out_size, void* d_ws, size_t ws_size,
                              hipStream_t stream)
{
    const float* x  = (const float*)d_in[0];
    const float* st = (const float*)d_in[1];
    const float* E  = (const float*)d_in[2];
    const float* gw = (const float*)d_in[3];
    const float* gb = (const float*)d_in[4];
    const float* uw = (const float*)d_in[5];
    const float* ub = (const float*)d_in[6];
    float* out = (float*)d_out;

    // fixed workspace layout (85.98 MB) + adaptive weight-chunk buffer
    unsigned char* ws = (unsigned char*)d_ws;
    unsigned short* S_hi = (unsigned short*)ws;                       // 8,388,608
    unsigned short* XT   = (unsigned short*)(ws + 8388608);           // 17,825,792
    unsigned short* IN   = (unsigned short*)(ws + 26214400);          // 41,943,040
    unsigned short* Rb   = (unsigned short*)(ws + 68157440);          // 16,777,216
    float* wpTg          = (float*)(ws + 84934656);                   //    696,320
    float* wpTu          = (float*)(ws + 85630976);                   //    348,160
    unsigned char* Wc    = ws + 85979136;

    // chunk size: largest power-of-two node count whose gate blobs fit
    const size_t fixed_b = 85979136;
    int C = 64;
    const int cands[5] = {2048, 1024, 512, 256, 128};
    for (int i = 0; i < 5; ++i) {
        if (ws_size >= fixed_b + (size_t)cands[i] * (2 * WBLOB)) { C = cands[i]; break; }
    }
    const int nch = N_NODES / C;

    const int tg = D_EMB * GOUT * KPAD;
    const int tu = D_EMB * DOUT * KPAD;
    transpose_pool_kernel<<<(tg + 255) / 256, 256, 0, stream>>>(gw, wpTg, GOUT, tg);
    transpose_pool_kernel<<<(tu + 255) / 256, 256, 0, stream>>>(uw, wpTu, DOUT, tu);

    supports_kernel<<<N_NODES, 256, 0, stream>>>(E, S_hi);
    zero_tail_kernel<<<(N_NODES * BATCH * 13 + 255) / 256, 256, 0, stream>>>(IN);
    build_xt_kernel<<<dim3(N_NODES / 64, BATCH), 256, 0, stream>>>(x, st, IN, 0, XT);
    gemm_mfma_kernel<<<544, 256, 0, stream>>>(S_hi, XT, IN);

    for (int ch = 0; ch < nch; ++ch) {
        const int n0 = ch * C;
        wgen_kernel<<<dim3(10, C / 16), 256, 0, stream>>>(E, wpTg, Wc, n0, 2, GOUT);
        gate_mfma_kernel<<<dim3(C, 2), 256, 0, stream>>>(E, gb, x, st, IN, Wc, n0, Rb);
    }

    build_xt_kernel<<<dim3(N_NODES / 64, BATCH), 256, 0, stream>>>(x, st, IN, 1, XT);
    gemm_mfma_kernel<<<544, 256, 0, stream>>>(S_hi, XT, IN);

    for (int ch = 0; ch < nch; ++ch) {
        const int n0 = ch * C;
        wgen_kernel<<<dim3(5, C / 16), 256, 0, stream>>>(E, wpTu, Wc, n0, 1, DOUT);
        update_mfma_kernel<<<C, 256, 0, stream>>>(E, ub, x, st, IN, Wc, n0, Rb, out);
    }
}